// Round 4
// baseline (626.119 us; speedup 1.0000x reference)
//
#include <hip/hip_runtime.h>

typedef __attribute__((ext_vector_type(8))) short short8;
typedef __attribute__((ext_vector_type(4))) float f32x4;

__device__ __forceinline__ unsigned short f2b(float f) {
  unsigned u = __float_as_uint(f);
  return (unsigned short)((u + 0x7FFFu + ((u >> 16) & 1u)) >> 16);
}
__device__ __forceinline__ float b2f(unsigned short h) {
  return __uint_as_float(((unsigned)h) << 16);
}
__device__ __forceinline__ int regf(int v) { return v < 49 ? 0 : (v < 53 ? 1 : 2); }
__device__ __forceinline__ float gelu_tanh(float v) {
  float c = 0.7978845608028654f * (v + 0.044715f * v * v * v);
  return 0.5f * v * (1.0f + tanhf(c));
}

// ---------------- k_misc: scales + CPB bias table ----------------
__global__ void k_misc(const float* __restrict__ logit_scale,
                       const float* __restrict__ w1, const float* __restrict__ b1,
                       const float* __restrict__ w2,
                       float* __restrict__ scales, float* __restrict__ bias16) {
  __shared__ float tbl[169][8];
  int t = threadIdx.x;
  if (t < 8) scales[t] = expf(fminf(logit_scale[t], logf(100.0f)));
  if (t < 169) {
    int a = t / 13, b = t % 13;
    float ra = (float)(a - 6) * (8.0f / 6.0f);
    float rb = (float)(b - 6) * (8.0f / 6.0f);
    float sa = (ra > 0.f) ? 1.f : ((ra < 0.f) ? -1.f : 0.f);
    float sb = (rb > 0.f) ? 1.f : ((rb < 0.f) ? -1.f : 0.f);
    float t0 = sa * log2f(fabsf(ra) + 1.0f) / 3.0f;
    float t1 = sb * log2f(fabsf(rb) + 1.0f) / 3.0f;
    float acc[8];
#pragma unroll
    for (int hh = 0; hh < 8; ++hh) acc[hh] = 0.f;
    for (int j = 0; j < 512; ++j) {
      float hv = fmaxf(w1[2*j] * t0 + w1[2*j+1] * t1 + b1[j], 0.0f);
#pragma unroll
      for (int hh = 0; hh < 8; ++hh) acc[hh] += w2[hh*512 + j] * hv;
    }
#pragma unroll
    for (int hh = 0; hh < 8; ++hh) tbl[t][hh] = acc[hh];
  }
  __syncthreads();
  for (int idx = t; idx < 8*49*49; idx += 256) {
    int hh = idx / 2401, rem = idx % 2401, p = rem / 49, q = rem % 49;
    int e = (p/7 - q/7 + 6) * 13 + (p%7 - q%7 + 6);
    float r = tbl[e][hh];
    bias16[idx] = 16.0f / (1.0f + expf(-r));
  }
}

// ---------------- k_cvt: weights fp32 -> bf16 ----------------
__global__ void k_cvt(const float* __restrict__ qkv_w, const float* __restrict__ proj_w,
                      const float* __restrict__ fc1_w, const float* __restrict__ fc2_w,
                      unsigned short* __restrict__ wq, unsigned short* __restrict__ wp,
                      unsigned short* __restrict__ w1, unsigned short* __restrict__ w2) {
  int i = blockIdx.x * 256 + threadIdx.x;
  if (i < 196608) wq[i] = f2b(qkv_w[i]);
  else if (i < 262144) wp[i - 196608] = f2b(proj_w[i - 196608]);
  else if (i < 524288) w1[i - 262144] = f2b(fc1_w[i - 262144]);
  else w2[i - 524288] = f2b(fc2_w[i - 524288]);
}

// ---------------- k_qkv: windowed QKV GEMM ----------------
__launch_bounds__(256)
__global__ void k_qkv(const float* __restrict__ x, const unsigned short* __restrict__ wq,
                      const float* __restrict__ q_bias, const float* __restrict__ v_bias,
                      unsigned short* __restrict__ qkv) {
  const int bx = blockIdx.x;
  const int win = bx / 3, which = bx % 3;
  const int b = win >> 6, wi = (win >> 3) & 7, wj = win & 7;
  const int t = threadIdx.x;
  const int lane = t & 63, w = t >> 6;
  const int wm = w >> 1, wn = w & 1;

  __shared__ __align__(16) char smem[64*528 + 256*80];
  unsigned short* As = (unsigned short*)smem;            // [64][264]
  unsigned short* Bs = (unsigned short*)(smem + 64*528); // [256][40]

#pragma unroll
  for (int it = 0; it < 8; ++it) {
    int cid = t + it * 256;
    int row = cid >> 5, cc = cid & 31;
    int4 pk;
    if (row < 49) {
      int i = row / 7, j = row % 7;
      int ho = (wi * 7 + i + 3) % 56;
      int wo = (wj * 7 + j + 3) % 56;
      const float* src = x + (size_t)(b * 3136 + ho * 56 + wo) * 256 + cc * 8;
      float4 f0 = *(const float4*)(src);
      float4 f1 = *(const float4*)(src + 4);
      pk.x = (unsigned)f2b(f0.x) | ((unsigned)f2b(f0.y) << 16);
      pk.y = (unsigned)f2b(f0.z) | ((unsigned)f2b(f0.w) << 16);
      pk.z = (unsigned)f2b(f1.x) | ((unsigned)f2b(f1.y) << 16);
      pk.w = (unsigned)f2b(f1.z) | ((unsigned)f2b(f1.w) << 16);
    } else {
      pk.x = pk.y = pk.z = pk.w = 0;
    }
    *(int4*)((char*)As + row * 528 + cc * 16) = pk;
  }

  f32x4 acc[2][8];
#pragma unroll
  for (int mf = 0; mf < 2; ++mf)
#pragma unroll
    for (int nf = 0; nf < 8; ++nf) acc[mf][nf] = (f32x4){0.f, 0.f, 0.f, 0.f};

  for (int k0 = 0; k0 < 256; k0 += 32) {
    __syncthreads();
    {
      const unsigned short* src = wq + ((size_t)(which * 256 + t)) * 256 + k0;
#pragma unroll
      for (int c = 0; c < 4; ++c)
        *(int4*)((char*)Bs + t * 80 + c * 16) = *(const int4*)(src + c * 8);
    }
    __syncthreads();
    short8 a_[2], b_[8];
    int kk = (lane >> 4) << 3;
#pragma unroll
    for (int mf = 0; mf < 2; ++mf) {
      int row = wm * 32 + mf * 16 + (lane & 15);
      a_[mf] = *(const short8*)((char*)As + row * 528 + (k0 + kk) * 2);
    }
#pragma unroll
    for (int nf = 0; nf < 8; ++nf) {
      int n = wn * 128 + nf * 16 + (lane & 15);
      b_[nf] = *(const short8*)((char*)Bs + n * 80 + kk * 2);
    }
#pragma unroll
    for (int mf = 0; mf < 2; ++mf)
#pragma unroll
      for (int nf = 0; nf < 8; ++nf)
        acc[mf][nf] = __builtin_amdgcn_mfma_f32_16x16x32_bf16(a_[mf], b_[nf], acc[mf][nf], 0, 0, 0);
  }

#pragma unroll
  for (int mf = 0; mf < 2; ++mf) {
    int rbase = wm * 32 + mf * 16 + ((lane >> 4) << 2);
#pragma unroll
    for (int nf = 0; nf < 8; ++nf) {
      int n = wn * 128 + nf * 16 + (lane & 15);
      float bias = (which == 0) ? q_bias[n] : ((which == 2) ? v_bias[n] : 0.0f);
      int head = n >> 5, d = n & 31;
#pragma unroll
      for (int j = 0; j < 4; ++j) {
        int row = rbase + j;
        if (row < 49) {
          size_t addr = ((((size_t)win * 3 + which) * 8 + head) * 49 + row) * 32 + d;
          qkv[addr] = f2b(acc[mf][nf][j] + bias);
        }
      }
    }
  }
}

// ---------------- k_attn: per-window attention + proj + LN + residual ----------------
__launch_bounds__(256)
__global__ void k_attn(const float* __restrict__ x, const unsigned short* __restrict__ qkv,
                       const unsigned short* __restrict__ wproj, const float* __restrict__ proj_b,
                       const float* __restrict__ n1w, const float* __restrict__ n1b,
                       const float* __restrict__ scales, const float* __restrict__ bias16,
                       float* __restrict__ x1) {
  const int win = blockIdx.x;
  const int b = win >> 6, wi = (win >> 3) & 7, wj = win & 7;
  const int t = threadIdx.x, lane = t & 63, w = t >> 6;
  const int wm = w >> 1, wn = w & 1;

  __shared__ __align__(16) char smem[75264];
  unsigned short* OB = (unsigned short*)smem;              // [64][264] bf16
  unsigned short* QN = (unsigned short*)(smem + 33792);    // [64][40]
  unsigned short* KN = (unsigned short*)(smem + 38912);    // [64][40]
  unsigned short* VT = (unsigned short*)(smem + 44032);    // [32][72]
  float*          SS = (float*)(smem + 48640);             // [64][68] f32
  unsigned short* PP = (unsigned short*)(smem + 66048);    // [64][72]
  unsigned short* BS = (unsigned short*)(smem + 33792);    // alias [256][40]
  float*          PR = (float*)smem;                       // alias [64][260] f32

  for (int h = 0; h < 8; ++h) {
    __syncthreads();
    const unsigned short* qp = qkv + ((((size_t)win * 3 + 0) * 8 + h) * 49) * 32;
    const unsigned short* kp = qkv + ((((size_t)win * 3 + 1) * 8 + h) * 49) * 32;
    const unsigned short* vp = qkv + ((((size_t)win * 3 + 2) * 8 + h) * 49) * 32;
    for (int idx = t; idx < 392; idx += 256) {
      int row = idx >> 3, c4 = (idx & 7) * 4;
      *(int2*)(QN + row * 40 + c4) = *(const int2*)(qp + row * 32 + c4);
      *(int2*)(KN + row * 40 + c4) = *(const int2*)(kp + row * 32 + c4);
      unsigned short vv[4];
      *(int2*)vv = *(const int2*)(vp + row * 32 + c4);
      VT[(c4 + 0) * 72 + row] = vv[0];
      VT[(c4 + 1) * 72 + row] = vv[1];
      VT[(c4 + 2) * 72 + row] = vv[2];
      VT[(c4 + 3) * 72 + row] = vv[3];
    }
    for (int idx = t; idx < 15 * 32; idx += 256) {   // zero pad rows 49..63
      int row = 49 + idx / 32, d = idx % 32;
      QN[row * 40 + d] = 0; KN[row * 40 + d] = 0;
      VT[d * 72 + row] = 0;
    }
    __syncthreads();
    if (t < 49) {
      float ss = 0.f;
      for (int d = 0; d < 32; ++d) { float v = b2f(QN[t * 40 + d]); ss += v * v; }
      float inv = scales[h] / fmaxf(sqrtf(ss), 1e-12f);
      for (int d = 0; d < 32; ++d) QN[t * 40 + d] = f2b(b2f(QN[t * 40 + d]) * inv);
    } else if (t >= 64 && t < 113) {
      int r = t - 64;
      float ss = 0.f;
      for (int d = 0; d < 32; ++d) { float v = b2f(KN[r * 40 + d]); ss += v * v; }
      float inv = 1.0f / fmaxf(sqrtf(ss), 1e-12f);
      for (int d = 0; d < 32; ++d) KN[r * 40 + d] = f2b(b2f(KN[r * 40 + d]) * inv);
    }
    __syncthreads();
    {
      short8 a_[2], b_[2];
      int kk = (lane >> 4) << 3;
#pragma unroll
      for (int mf = 0; mf < 2; ++mf)
        a_[mf] = *(const short8*)(QN + (wm * 32 + mf * 16 + (lane & 15)) * 40 + kk);
#pragma unroll
      for (int nf = 0; nf < 2; ++nf)
        b_[nf] = *(const short8*)(KN + (wn * 32 + nf * 16 + (lane & 15)) * 40 + kk);
      f32x4 sacc[2][2];
#pragma unroll
      for (int mf = 0; mf < 2; ++mf)
#pragma unroll
        for (int nf = 0; nf < 2; ++nf) {
          sacc[mf][nf] = (f32x4){0.f, 0.f, 0.f, 0.f};
          sacc[mf][nf] = __builtin_amdgcn_mfma_f32_16x16x32_bf16(a_[mf], b_[nf], sacc[mf][nf], 0, 0, 0);
        }
#pragma unroll
      for (int mf = 0; mf < 2; ++mf)
#pragma unroll
        for (int nf = 0; nf < 2; ++nf)
#pragma unroll
          for (int j = 0; j < 4; ++j) {
            int row = wm * 32 + mf * 16 + ((lane >> 4) << 2) + j;
            int col = wn * 32 + nf * 16 + (lane & 15);
            if (row < 49 && col < 49) {
              float v = sacc[mf][nf][j] + bias16[(h * 49 + row) * 49 + col];
              int rr = regf(wi * 7 + row / 7) * 3 + regf(wj * 7 + row % 7);
              int rc = regf(wi * 7 + col / 7) * 3 + regf(wj * 7 + col % 7);
              if (rr != rc) v -= 100.0f;
              SS[row * 68 + col] = v;
            }
          }
    }
    __syncthreads();
    {
      int row = t >> 2, sub = t & 3;
      if (row < 49) {
        float m = -1e30f;
        for (int j = sub; j < 49; j += 4) m = fmaxf(m, SS[row * 68 + j]);
        m = fmaxf(m, __shfl_xor(m, 1));
        m = fmaxf(m, __shfl_xor(m, 2));
        float s = 0.f;
        for (int j = sub; j < 49; j += 4) {
          float e = expf(SS[row * 68 + j] - m);
          SS[row * 68 + j] = e; s += e;
        }
        s += __shfl_xor(s, 1); s += __shfl_xor(s, 2);
        float inv = 1.0f / s;
        for (int j = sub; j < 64; j += 4)
          PP[row * 72 + j] = (j < 49) ? f2b(SS[row * 68 + j] * inv) : (unsigned short)0;
      } else {
        for (int j = sub; j < 64; j += 4) PP[row * 72 + j] = 0;
      }
    }
    __syncthreads();
    {
      f32x4 pacc[2];
      pacc[0] = (f32x4){0.f, 0.f, 0.f, 0.f};
      pacc[1] = (f32x4){0.f, 0.f, 0.f, 0.f};
#pragma unroll
      for (int ks = 0; ks < 2; ++ks) {
        int kk = ks * 32 + ((lane >> 4) << 3);
        short8 bv = *(const short8*)(VT + (wn * 16 + (lane & 15)) * 72 + kk);
#pragma unroll
        for (int mf = 0; mf < 2; ++mf) {
          short8 pa = *(const short8*)(PP + (wm * 32 + mf * 16 + (lane & 15)) * 72 + kk);
          pacc[mf] = __builtin_amdgcn_mfma_f32_16x16x32_bf16(pa, bv, pacc[mf], 0, 0, 0);
        }
      }
#pragma unroll
      for (int mf = 0; mf < 2; ++mf)
#pragma unroll
        for (int j = 0; j < 4; ++j) {
          int row = wm * 32 + mf * 16 + ((lane >> 4) << 2) + j;
          int col = h * 32 + wn * 16 + (lane & 15);
          OB[row * 264 + col] = f2b(pacc[mf][j]);
        }
    }
  }

  __syncthreads();
  f32x4 acc[2][8];
#pragma unroll
  for (int mf = 0; mf < 2; ++mf)
#pragma unroll
    for (int nf = 0; nf < 8; ++nf) acc[mf][nf] = (f32x4){0.f, 0.f, 0.f, 0.f};
  for (int k0 = 0; k0 < 256; k0 += 32) {
    __syncthreads();
    {
      const unsigned short* src = wproj + (size_t)t * 256 + k0;
#pragma unroll
      for (int c = 0; c < 4; ++c)
        *(int4*)((char*)BS + t * 80 + c * 16) = *(const int4*)(src + c * 8);
    }
    __syncthreads();
    short8 a_[2], b_[8];
    int kk = (lane >> 4) << 3;
#pragma unroll
    for (int mf = 0; mf < 2; ++mf) {
      int row = wm * 32 + mf * 16 + (lane & 15);
      a_[mf] = *(const short8*)((char*)OB + row * 528 + (k0 + kk) * 2);
    }
#pragma unroll
    for (int nf = 0; nf < 8; ++nf) {
      int n = wn * 128 + nf * 16 + (lane & 15);
      b_[nf] = *(const short8*)((char*)BS + n * 80 + kk * 2);
    }
#pragma unroll
    for (int mf = 0; mf < 2; ++mf)
#pragma unroll
      for (int nf = 0; nf < 8; ++nf)
        acc[mf][nf] = __builtin_amdgcn_mfma_f32_16x16x32_bf16(a_[mf], b_[nf], acc[mf][nf], 0, 0, 0);
  }
  __syncthreads();
#pragma unroll
  for (int mf = 0; mf < 2; ++mf)
#pragma unroll
    for (int nf = 0; nf < 8; ++nf)
#pragma unroll
      for (int j = 0; j < 4; ++j) {
        int row = wm * 32 + mf * 16 + ((lane >> 4) << 2) + j;
        int col = wn * 128 + nf * 16 + (lane & 15);
        PR[row * 260 + col] = acc[mf][nf][j] + proj_b[col];
      }
  __syncthreads();
  {
    int row = t >> 2, sub = t & 3;
    if (row < 49) {
      float s = 0.f, s2 = 0.f;
      for (int i = 0; i < 16; ++i) {
        int c = sub * 4 + i * 16;
        float4 pv = *(float4*)(PR + row * 260 + c);
        s += pv.x + pv.y + pv.z + pv.w;
        s2 += pv.x * pv.x + pv.y * pv.y + pv.z * pv.z + pv.w * pv.w;
      }
      s += __shfl_xor(s, 1); s += __shfl_xor(s, 2);
      s2 += __shfl_xor(s2, 1); s2 += __shfl_xor(s2, 2);
      float mu = s * (1.0f / 256.0f);
      float var = s2 * (1.0f / 256.0f) - mu * mu;
      float rs = rsqrtf(var + 1e-5f);
      int i2 = row / 7, j2 = row % 7;
      int ho = (wi * 7 + i2 + 3) % 56, wo = (wj * 7 + j2 + 3) % 56;
      size_t base = (size_t)(b * 3136 + ho * 56 + wo) * 256;
      for (int i = 0; i < 16; ++i) {
        int c = sub * 4 + i * 16;
        float4 pv = *(float4*)(PR + row * 260 + c);
        float4 xv = *(const float4*)(x + base + c);
        float4 o;
        o.x = xv.x + (pv.x - mu) * rs * n1w[c + 0] + n1b[c + 0];
        o.y = xv.y + (pv.y - mu) * rs * n1w[c + 1] + n1b[c + 1];
        o.z = xv.z + (pv.z - mu) * rs * n1w[c + 2] + n1b[c + 2];
        o.w = xv.w + (pv.w - mu) * rs * n1w[c + 3] + n1b[c + 3];
        *(float4*)(x1 + base + c) = o;
      }
    }
  }
}

// ---------------- k_fc1: H = gelu(x1 @ W1^T + b1), 128x128 tile ----------------
__launch_bounds__(256)
__global__ void k_fc1(const float* __restrict__ x1, const unsigned short* __restrict__ w1,
                      const float* __restrict__ b1, unsigned short* __restrict__ Hbuf, int r0) {
  const int mb = blockIdx.x, nb = blockIdx.y;
  const int t = threadIdx.x, lane = t & 63, w = t >> 6;
  const int wm = w >> 1, wn = w & 1;
  const int l15 = lane & 15, kk8 = (lane >> 4) << 3, rj = (lane >> 4) << 2;

  __shared__ __align__(16) char smem[36864];
  unsigned short* As = (unsigned short*)smem;            // [128][72]
  unsigned short* Bs = (unsigned short*)(smem + 18432);  // [128][72]

  f32x4 acc[4][4];
#pragma unroll
  for (int mf = 0; mf < 4; ++mf)
#pragma unroll
    for (int nf = 0; nf < 4; ++nf) acc[mf][nf] = (f32x4){0.f, 0.f, 0.f, 0.f};

  const int row_g0 = r0 + mb * 128;
  const int srow = t >> 1, sh = t & 1;

  for (int kb = 0; kb < 4; ++kb) {
    __syncthreads();
    {
      const float* src = x1 + (size_t)(row_g0 + srow) * 256 + kb * 64 + sh * 32;
#pragma unroll
      for (int c = 0; c < 4; ++c) {
        float4 f0 = *(const float4*)(src + c * 8);
        float4 f1 = *(const float4*)(src + c * 8 + 4);
        int4 pk;
        pk.x = (unsigned)f2b(f0.x) | ((unsigned)f2b(f0.y) << 16);
        pk.y = (unsigned)f2b(f0.z) | ((unsigned)f2b(f0.w) << 16);
        pk.z = (unsigned)f2b(f1.x) | ((unsigned)f2b(f1.y) << 16);
        pk.w = (unsigned)f2b(f1.z) | ((unsigned)f2b(f1.w) << 16);
        *(int4*)((char*)As + srow * 144 + sh * 64 + c * 16) = pk;
      }
      const unsigned short* srcb = w1 + (size_t)(nb * 128 + srow) * 256 + kb * 64 + sh * 32;
#pragma unroll
      for (int c = 0; c < 4; ++c)
        *(int4*)((char*)Bs + srow * 144 + sh * 64 + c * 16) = *(const int4*)(srcb + c * 8);
    }
    __syncthreads();
#pragma unroll
    for (int ks = 0; ks < 2; ++ks) {
      int ko = ks * 32 + kk8;
      short8 a_[4], b_[4];
#pragma unroll
      for (int mf = 0; mf < 4; ++mf)
        a_[mf] = *(const short8*)((char*)As + (wm * 64 + mf * 16 + l15) * 144 + ko * 2);
#pragma unroll
      for (int nf = 0; nf < 4; ++nf)
        b_[nf] = *(const short8*)((char*)Bs + (wn * 64 + nf * 16 + l15) * 144 + ko * 2);
#pragma unroll
      for (int mf = 0; mf < 4; ++mf)
#pragma unroll
        for (int nf = 0; nf < 4; ++nf)
          acc[mf][nf] = __builtin_amdgcn_mfma_f32_16x16x32_bf16(a_[mf], b_[nf], acc[mf][nf], 0, 0, 0);
    }
  }
  // epilogue: bias + gelu -> H bf16 (pass-local rows)
#pragma unroll
  for (int mf = 0; mf < 4; ++mf)
#pragma unroll
    for (int nf = 0; nf < 4; ++nf) {
      int col = nb * 128 + wn * 64 + nf * 16 + l15;
      float bias = b1[col];
#pragma unroll
      for (int j = 0; j < 4; ++j) {
        int row = mb * 128 + wm * 64 + mf * 16 + rj + j;
        Hbuf[(size_t)row * 1024 + col] = f2b(gelu_tanh(acc[mf][nf][j] + bias));
      }
    }
}

// ---------------- k_fc2: out = x1 + LN(H @ W2^T + b2), 128x256 tile, 8 waves ----------------
__launch_bounds__(512)
__global__ void k_fc2(const unsigned short* __restrict__ Hbuf, const unsigned short* __restrict__ w2,
                      const float* __restrict__ b2, const float* __restrict__ n2w,
                      const float* __restrict__ n2b, float* __restrict__ xio, int r0) {
  const int mb = blockIdx.x;
  const int t = threadIdx.x, lane = t & 63, w = t >> 6;   // 8 waves
  const int wm = w >> 1, wn = w & 1;                      // wm 0..3 (32-row), wn 0..1 (128-col)
  const int l15 = lane & 15, kk8 = (lane >> 4) << 3, rj = (lane >> 4) << 2;

  __shared__ __align__(16) char smem[57344];
  unsigned short* As = (unsigned short*)smem;             // [128][72]  H rows
  unsigned short* Bs = (unsigned short*)(smem + 18432);   // [256][72]  W2 rows
  float*          RED = (float*)(smem + 55296);           // [128][2][2] {s,s2} per col-half

  f32x4 acc[2][8];
#pragma unroll
  for (int mf = 0; mf < 2; ++mf)
#pragma unroll
    for (int nf = 0; nf < 8; ++nf) acc[mf][nf] = (f32x4){0.f, 0.f, 0.f, 0.f};

  for (int kb = 0; kb < 16; ++kb) {
    __syncthreads();
    {
      int arow = t >> 2, aq = t & 3;     // A: 128 rows x 64 cols bf16, 32 B/thread
      const unsigned short* srca = Hbuf + (size_t)(mb * 128 + arow) * 1024 + kb * 64 + aq * 16;
      *(int4*)((char*)As + arow * 144 + aq * 32) = *(const int4*)(srca);
      *(int4*)((char*)As + arow * 144 + aq * 32 + 16) = *(const int4*)(srca + 8);
      int brow = t >> 1, bh = t & 1;     // B: 256 rows x 64 cols bf16, 64 B/thread
      const unsigned short* srcb = w2 + (size_t)brow * 1024 + kb * 64 + bh * 32;
#pragma unroll
      for (int c = 0; c < 4; ++c)
        *(int4*)((char*)Bs + brow * 144 + bh * 64 + c * 16) = *(const int4*)(srcb + c * 8);
    }
    __syncthreads();
#pragma unroll
    for (int ks = 0; ks < 2; ++ks) {
      int ko = ks * 32 + kk8;
      short8 a_[2], b_[8];
#pragma unroll
      for (int mf = 0; mf < 2; ++mf)
        a_[mf] = *(const short8*)((char*)As + (wm * 32 + mf * 16 + l15) * 144 + ko * 2);
#pragma unroll
      for (int nf = 0; nf < 8; ++nf)
        b_[nf] = *(const short8*)((char*)Bs + (wn * 128 + nf * 16 + l15) * 144 + ko * 2);
#pragma unroll
      for (int mf = 0; mf < 2; ++mf)
#pragma unroll
        for (int nf = 0; nf < 8; ++nf)
          acc[mf][nf] = __builtin_amdgcn_mfma_f32_16x16x32_bf16(a_[mf], b_[nf], acc[mf][nf], 0, 0, 0);
    }
  }

  // add bias into acc; per-row partial sums over this wave's 128 cols
#pragma unroll
  for (int nf = 0; nf < 8; ++nf) {
    float bias = b2[wn * 128 + nf * 16 + l15];
#pragma unroll
    for (int mf = 0; mf < 2; ++mf)
#pragma unroll
      for (int j = 0; j < 4; ++j) acc[mf][nf][j] += bias;
  }
#pragma unroll
  for (int mf = 0; mf < 2; ++mf)
#pragma unroll
    for (int j = 0; j < 4; ++j) {
      float s = 0.f, s2 = 0.f;
#pragma unroll
      for (int nf = 0; nf < 8; ++nf) {
        float v = acc[mf][nf][j];
        s += v; s2 += v * v;
      }
      s += __shfl_xor(s, 1);  s += __shfl_xor(s, 2);  s += __shfl_xor(s, 4);  s += __shfl_xor(s, 8);
      s2 += __shfl_xor(s2, 1); s2 += __shfl_xor(s2, 2); s2 += __shfl_xor(s2, 4); s2 += __shfl_xor(s2, 8);
      if (l15 == 0) {
        int row = wm * 32 + mf * 16 + rj + j;
        RED[(row * 2 + wn) * 2 + 0] = s;
        RED[(row * 2 + wn) * 2 + 1] = s2;
      }
    }
  __syncthreads();
#pragma unroll
  for (int mf = 0; mf < 2; ++mf)
#pragma unroll
    for (int j = 0; j < 4; ++j) {
      int row = wm * 32 + mf * 16 + rj + j;
      float ts = RED[(row * 2 + 0) * 2 + 0] + RED[(row * 2 + 1) * 2 + 0];
      float ts2 = RED[(row * 2 + 0) * 2 + 1] + RED[(row * 2 + 1) * 2 + 1];
      float mu = ts * (1.0f / 256.0f);
      float var = ts2 * (1.0f / 256.0f) - mu * mu;
      float rs = rsqrtf(var + 1e-5f);
      size_t base = (size_t)(r0 + mb * 128 + row) * 256;
#pragma unroll
      for (int nf = 0; nf < 8; ++nf) {
        int col = wn * 128 + nf * 16 + l15;
        float xv = xio[base + col];
        xio[base + col] = xv + (acc[mf][nf][j] - mu) * rs * n2w[col] + n2b[col];
      }
    }
}

extern "C" void kernel_launch(void* const* d_in, const int* in_sizes, int n_in,
                              void* d_out, int out_size, void* d_ws, size_t ws_size,
                              hipStream_t stream) {
  const float* x           = (const float*)d_in[0];
  const float* norm1_w     = (const float*)d_in[1];
  const float* norm1_b     = (const float*)d_in[2];
  const float* qkv_w       = (const float*)d_in[3];
  const float* q_bias      = (const float*)d_in[4];
  const float* v_bias      = (const float*)d_in[5];
  const float* logit_scale = (const float*)d_in[6];
  const float* cpb_w1      = (const float*)d_in[7];
  const float* cpb_b1      = (const float*)d_in[8];
  const float* cpb_w2      = (const float*)d_in[9];
  const float* proj_w      = (const float*)d_in[10];
  const float* proj_b      = (const float*)d_in[11];
  const float* norm2_w     = (const float*)d_in[12];
  const float* norm2_b     = (const float*)d_in[13];
  const float* fc1_w       = (const float*)d_in[14];
  const float* fc1_b       = (const float*)d_in[15];
  const float* fc2_w       = (const float*)d_in[16];
  const float* fc2_b       = (const float*)d_in[17];
  float* out = (float*)d_out;

  char* ws = (char*)d_ws;
  float*          scales  = (float*)(ws + 0);
  float*          bias16  = (float*)(ws + 512);
  unsigned short* wq      = (unsigned short*)(ws + 77824);
  unsigned short* wp      = (unsigned short*)(ws + 471040);
  unsigned short* w1b     = (unsigned short*)(ws + 602112);
  unsigned short* w2b     = (unsigned short*)(ws + 1126400);
  unsigned short* qkvbuf  = (unsigned short*)(ws + 1650688);
  // H-half (25088 x 1024 bf16 = 51.4 MB) reuses the qkvbuf region (dead after k_attn)
  unsigned short* Hbuf    = (unsigned short*)(ws + 1650688);
  float*          x1      = out;   // x1 lives in d_out; fc2 is row-local and overwrites in place

  k_misc<<<dim3(1), dim3(256), 0, stream>>>(logit_scale, cpb_w1, cpb_b1, cpb_w2, scales, bias16);
  k_cvt<<<dim3(3072), dim3(256), 0, stream>>>(qkv_w, proj_w, fc1_w, fc2_w, wq, wp, w1b, w2b);
  k_qkv<<<dim3(3072), dim3(256), 0, stream>>>(x, wq, q_bias, v_bias, qkvbuf);
  k_attn<<<dim3(1024), dim3(256), 0, stream>>>(x, qkvbuf, wp, proj_b, norm1_w, norm1_b, scales, bias16, x1);
  // MLP in two row-passes (H-half reuses qkvbuf region; fits proven ws footprint)
  k_fc1<<<dim3(196, 8), dim3(256), 0, stream>>>(x1, w1b, fc1_b, Hbuf, 0);
  k_fc2<<<dim3(196), dim3(512), 0, stream>>>(Hbuf, w2b, fc2_b, norm2_w, norm2_b, x1, 0);
  k_fc1<<<dim3(196, 8), dim3(256), 0, stream>>>(x1, w1b, fc1_b, Hbuf, 25088);
  k_fc2<<<dim3(196), dim3(512), 0, stream>>>(Hbuf, w2b, fc2_b, norm2_w, norm2_b, x1, 25088);
}

// Round 5
// 538.247 us; speedup vs baseline: 1.1633x; 1.1633x over previous
//
#include <hip/hip_runtime.h>

typedef __attribute__((ext_vector_type(8))) short short8;
typedef __attribute__((ext_vector_type(4))) float f32x4;

__device__ __forceinline__ unsigned short f2b(float f) {
  unsigned u = __float_as_uint(f);
  return (unsigned short)((u + 0x7FFFu + ((u >> 16) & 1u)) >> 16);
}
__device__ __forceinline__ float b2f(unsigned short h) {
  return __uint_as_float(((unsigned)h) << 16);
}
__device__ __forceinline__ float gelu_tanh(float v) {
  float c = 0.7978845608028654f * (v + 0.044715f * v * v * v);
  return 0.5f * v * (1.0f + tanhf(c));
}

// ---------------- k_misc: scales + CPB table (raw, per rel-coord) ----------------
__global__ void k_misc(const float* __restrict__ logit_scale,
                       const float* __restrict__ w1, const float* __restrict__ b1,
                       const float* __restrict__ w2,
                       float* __restrict__ scales, float* __restrict__ tblg) {
  int t = threadIdx.x;
  if (t < 8) scales[t] = expf(fminf(logit_scale[t], logf(100.0f)));
  if (t < 169) {
    int a = t / 13, b = t % 13;
    float ra = (float)(a - 6) * (8.0f / 6.0f);
    float rb = (float)(b - 6) * (8.0f / 6.0f);
    float sa = (ra > 0.f) ? 1.f : ((ra < 0.f) ? -1.f : 0.f);
    float sb = (rb > 0.f) ? 1.f : ((rb < 0.f) ? -1.f : 0.f);
    float t0 = sa * log2f(fabsf(ra) + 1.0f) / 3.0f;
    float t1 = sb * log2f(fabsf(rb) + 1.0f) / 3.0f;
    float acc[8];
#pragma unroll
    for (int hh = 0; hh < 8; ++hh) acc[hh] = 0.f;
    for (int j = 0; j < 512; ++j) {
      float hv = fmaxf(w1[2*j] * t0 + w1[2*j+1] * t1 + b1[j], 0.0f);
#pragma unroll
      for (int hh = 0; hh < 8; ++hh) acc[hh] += w2[hh*512 + j] * hv;
    }
#pragma unroll
    for (int hh = 0; hh < 8; ++hh) tblg[t * 8 + hh] = acc[hh];
  }
}

// ---------------- k_bias: biasT[h][k][q] padded 64x64, pad=-3e8 ----------------
__global__ void k_bias(const float* __restrict__ tblg, float* __restrict__ biasT) {
  int idx = blockIdx.x * 256 + threadIdx.x;   // 8*64*64 = 32768
  int h = idx >> 12, rem = idx & 4095, k = rem >> 6, q = rem & 63;
  float v;
  if (k >= 49 || q >= 49) {
    v = -3.0e8f;
  } else {
    int e = (q / 7 - k / 7 + 6) * 13 + (q % 7 - k % 7 + 6);
    float r = tblg[e * 8 + h];
    v = 16.0f / (1.0f + expf(-r));
  }
  biasT[idx] = v;
}

// ---------------- k_cvt: weights fp32 -> bf16 ----------------
__global__ void k_cvt(const float* __restrict__ qkv_w, const float* __restrict__ proj_w,
                      const float* __restrict__ fc1_w, const float* __restrict__ fc2_w,
                      unsigned short* __restrict__ wq, unsigned short* __restrict__ wp,
                      unsigned short* __restrict__ w1, unsigned short* __restrict__ w2) {
  int i = blockIdx.x * 256 + threadIdx.x;
  if (i < 196608) wq[i] = f2b(qkv_w[i]);
  else if (i < 262144) wp[i - 196608] = f2b(proj_w[i - 196608]);
  else if (i < 524288) w1[i - 262144] = f2b(fc1_w[i - 262144]);
  else w2[i - 524288] = f2b(fc2_w[i - 524288]);
}

// ---------------- k_qkv: windowed QKV GEMM + fused q/k normalization ----------------
__launch_bounds__(256)
__global__ void k_qkv(const float* __restrict__ x, const unsigned short* __restrict__ wq,
                      const float* __restrict__ q_bias, const float* __restrict__ v_bias,
                      const float* __restrict__ scales, unsigned short* __restrict__ qkv) {
  const int bx = blockIdx.x;
  const int win = bx / 3, which = bx % 3;
  const int b = win >> 6, wi = (win >> 3) & 7, wj = win & 7;
  const int t = threadIdx.x;
  const int lane = t & 63, w = t >> 6;
  const int wm = w >> 1, wn = w & 1;

  __shared__ __align__(16) char smem[64*528 + 256*80];
  unsigned short* As = (unsigned short*)smem;            // [64][264]
  unsigned short* Bs = (unsigned short*)(smem + 64*528); // [256][40]

#pragma unroll
  for (int it = 0; it < 8; ++it) {
    int cid = t + it * 256;
    int row = cid >> 5, cc = cid & 31;
    int4 pk;
    if (row < 49) {
      int i = row / 7, j = row % 7;
      int ho = (wi * 7 + i + 3) % 56;
      int wo = (wj * 7 + j + 3) % 56;
      const float* src = x + (size_t)(b * 3136 + ho * 56 + wo) * 256 + cc * 8;
      float4 f0 = *(const float4*)(src);
      float4 f1 = *(const float4*)(src + 4);
      pk.x = (unsigned)f2b(f0.x) | ((unsigned)f2b(f0.y) << 16);
      pk.y = (unsigned)f2b(f0.z) | ((unsigned)f2b(f0.w) << 16);
      pk.z = (unsigned)f2b(f1.x) | ((unsigned)f2b(f1.y) << 16);
      pk.w = (unsigned)f2b(f1.z) | ((unsigned)f2b(f1.w) << 16);
    } else {
      pk.x = pk.y = pk.z = pk.w = 0;
    }
    *(int4*)((char*)As + row * 528 + cc * 16) = pk;
  }

  f32x4 acc[2][8];
#pragma unroll
  for (int mf = 0; mf < 2; ++mf)
#pragma unroll
    for (int nf = 0; nf < 8; ++nf) acc[mf][nf] = (f32x4){0.f, 0.f, 0.f, 0.f};

  for (int k0 = 0; k0 < 256; k0 += 32) {
    __syncthreads();
    {
      const unsigned short* src = wq + ((size_t)(which * 256 + t)) * 256 + k0;
#pragma unroll
      for (int c = 0; c < 4; ++c)
        *(int4*)((char*)Bs + t * 80 + c * 16) = *(const int4*)(src + c * 8);
    }
    __syncthreads();
    short8 a_[2], b_[8];
    int kk = (lane >> 4) << 3;
#pragma unroll
    for (int mf = 0; mf < 2; ++mf) {
      int row = wm * 32 + mf * 16 + (lane & 15);
      a_[mf] = *(const short8*)((char*)As + row * 528 + (k0 + kk) * 2);
    }
#pragma unroll
    for (int nf = 0; nf < 8; ++nf) {
      int n = wn * 128 + nf * 16 + (lane & 15);
      b_[nf] = *(const short8*)((char*)Bs + n * 80 + kk * 2);
    }
#pragma unroll
    for (int mf = 0; mf < 2; ++mf)
#pragma unroll
      for (int nf = 0; nf < 8; ++nf)
        acc[mf][nf] = __builtin_amdgcn_mfma_f32_16x16x32_bf16(a_[mf], b_[nf], acc[mf][nf], 0, 0, 0);
  }

  // bias add (q/v only)
  if (which != 1) {
    const float* bp = (which == 0) ? q_bias : v_bias;
#pragma unroll
    for (int nf = 0; nf < 8; ++nf) {
      float bias = bp[wn * 128 + nf * 16 + (lane & 15)];
#pragma unroll
      for (int mf = 0; mf < 2; ++mf)
#pragma unroll
        for (int j = 0; j < 4; ++j) acc[mf][nf][j] += bias;
    }
  }
  // q/k: per-row L2-normalize over the head's 32 cols (pairs of nf frags, 16 lanes)
  if (which < 2) {
#pragma unroll
    for (int mf = 0; mf < 2; ++mf)
#pragma unroll
      for (int p = 0; p < 4; ++p)
#pragma unroll
        for (int j = 0; j < 4; ++j) {
          float ss = acc[mf][2*p][j] * acc[mf][2*p][j] + acc[mf][2*p+1][j] * acc[mf][2*p+1][j];
          ss += __shfl_xor(ss, 1); ss += __shfl_xor(ss, 2);
          ss += __shfl_xor(ss, 4); ss += __shfl_xor(ss, 8);
          float inv = 1.0f / fmaxf(sqrtf(ss), 1e-12f);
          if (which == 0) inv *= scales[wn * 4 + p];
          acc[mf][2*p][j] *= inv;
          acc[mf][2*p+1][j] *= inv;
        }
  }

  // scatter to [win][3][head][49][32] bf16
#pragma unroll
  for (int mf = 0; mf < 2; ++mf) {
    int rbase = wm * 32 + mf * 16 + ((lane >> 4) << 2);
#pragma unroll
    for (int nf = 0; nf < 8; ++nf) {
      int n = wn * 128 + nf * 16 + (lane & 15);
      int head = n >> 5, d = n & 31;
#pragma unroll
      for (int j = 0; j < 4; ++j) {
        int row = rbase + j;
        if (row < 49) {
          size_t addr = ((((size_t)win * 3 + which) * 8 + head) * 49 + row) * 32 + d;
          qkv[addr] = f2b(acc[mf][nf][j]);
        }
      }
    }
  }
}

// ---------------- k_attn: swapped-QK^T per-wave attention + proj + LN ----------------
__launch_bounds__(256)
__global__ void k_attn(const float* __restrict__ x, const unsigned short* __restrict__ qkv,
                       const unsigned short* __restrict__ wproj, const float* __restrict__ proj_b,
                       const float* __restrict__ n1w, const float* __restrict__ n1b,
                       const float* __restrict__ biasT, float* __restrict__ x1) {
  const int win = blockIdx.x;
  const int b = win >> 6, wi = (win >> 3) & 7, wj = win & 7;
  const int t = threadIdx.x, lane = t & 63, w = t >> 6;
  const int l15 = lane & 15, g = lane >> 4;
  const int kk8 = g << 3, rj = g << 2;

  __shared__ __align__(16) char smem[73728];
  unsigned short* VT8 = (unsigned short*)smem;                        // [8][32][72]
  unsigned short* PP  = (unsigned short*)(smem + 36864) + w * 4608;   // per-wave [64][72]
  unsigned short* OB  = (unsigned short*)smem;                        // alias: [64][264]
  unsigned short* BSp = (unsigned short*)(smem + 36864);              // alias: [256][72]
  float*          PR  = (float*)smem;                                 // alias: [64][260]

  const int vi = (wi == 7) ? 1 : 0, vj = (wj == 7) ? 1 : 0;

  // stage V transposed for all 8 heads; zero-pad k=49..63
  for (int idx = t; idx < 392; idx += 256) {
    int h = idx / 49, r = idx % 49;
    const unsigned short* vp = qkv + ((((size_t)win * 3 + 2) * 8 + h) * 49 + r) * 32;
    unsigned short vv[32];
    *(int4*)(vv + 0)  = *(const int4*)(vp + 0);
    *(int4*)(vv + 8)  = *(const int4*)(vp + 8);
    *(int4*)(vv + 16) = *(const int4*)(vp + 16);
    *(int4*)(vv + 24) = *(const int4*)(vp + 24);
    unsigned short* dst = VT8 + h * 2304;
#pragma unroll
    for (int d = 0; d < 32; ++d) dst[d * 72 + r] = vv[d];
  }
  for (int idx = t; idx < 3840; idx += 256) {
    int h = idx / 480, rem = idx % 480, d = rem / 15, r = 49 + rem % 15;
    VT8[h * 2304 + d * 72 + r] = 0;
  }
  __syncthreads();

  f32x4 o[2][8];
  for (int hh = 0; hh < 2; ++hh) {
    const int h = w + hh * 4;
    const float* bT = biasT + (size_t)h * 4096;
    // S^T acc init = bias (+ shift mask)
    f32x4 s[4][4];
#pragma unroll
    for (int mf = 0; mf < 4; ++mf)
#pragma unroll
      for (int nf = 0; nf < 4; ++nf)
#pragma unroll
        for (int j = 0; j < 4; ++j)
          s[mf][nf][j] = bT[(mf * 16 + rj + j) * 64 + nf * 16 + l15];
    if (vi | vj) {
      int rq[4];
#pragma unroll
      for (int nf = 0; nf < 4; ++nf) {
        int q = nf * 16 + l15, qi = q / 7, qj = q - qi * 7;
        int aq = vi ? (qi < 4 ? 1 : 2) : 0;
        int bq = vj ? (qj < 4 ? 1 : 2) : 0;
        rq[nf] = aq * 3 + bq;
      }
#pragma unroll
      for (int mf = 0; mf < 4; ++mf)
#pragma unroll
        for (int j = 0; j < 4; ++j) {
          int k = mf * 16 + rj + j, ki = k / 7, kj = k - ki * 7;
          int ak = vi ? (ki < 4 ? 1 : 2) : 0;
          int bk = vj ? (kj < 4 ? 1 : 2) : 0;
          int rk = ak * 3 + bk;
#pragma unroll
          for (int nf = 0; nf < 4; ++nf)
            if (rq[nf] != rk) s[mf][nf][j] -= 100.0f;
        }
    }
    // K, Q fragments straight from global (normalized+scaled already)
    const unsigned short* kp = qkv + (((size_t)win * 3 + 1) * 8 + h) * 1568;
    const unsigned short* qp = qkv + (((size_t)win * 3 + 0) * 8 + h) * 1568;
    short8 ka[4], qa[4];
#pragma unroll
    for (int f = 0; f < 4; ++f) {
      ka[f] = *(const short8*)(kp + (f * 16 + l15) * 32 + kk8);
      qa[f] = *(const short8*)(qp + (f * 16 + l15) * 32 + kk8);
    }
#pragma unroll
    for (int mf = 0; mf < 4; ++mf)
#pragma unroll
      for (int nf = 0; nf < 4; ++nf)
        s[mf][nf] = __builtin_amdgcn_mfma_f32_16x16x32_bf16(ka[mf], qa[nf], s[mf][nf], 0, 0, 0);

    // softmax over k (in-lane 16 + 2 shfls), write P[q][k] bf16 to per-wave PP
#pragma unroll
    for (int nf = 0; nf < 4; ++nf) {
      float m = -3.0e8f;
#pragma unroll
      for (int mf = 0; mf < 4; ++mf)
#pragma unroll
        for (int j = 0; j < 4; ++j) m = fmaxf(m, s[mf][nf][j]);
      m = fmaxf(m, __shfl_xor(m, 16));
      m = fmaxf(m, __shfl_xor(m, 32));
      float sum = 0.f;
#pragma unroll
      for (int mf = 0; mf < 4; ++mf)
#pragma unroll
        for (int j = 0; j < 4; ++j) {
          float e = __expf(s[mf][nf][j] - m);
          s[mf][nf][j] = e; sum += e;
        }
      sum += __shfl_xor(sum, 16);
      sum += __shfl_xor(sum, 32);
      float inv = 1.0f / sum;
      unsigned short* pq = PP + (nf * 16 + l15) * 72;
#pragma unroll
      for (int mf = 0; mf < 4; ++mf) {
        int2 pk;
        pk.x = (int)((unsigned)f2b(s[mf][nf][0] * inv) | ((unsigned)f2b(s[mf][nf][1] * inv) << 16));
        pk.y = (int)((unsigned)f2b(s[mf][nf][2] * inv) | ((unsigned)f2b(s[mf][nf][3] * inv) << 16));
        *(int2*)(pq + mf * 16 + rj) = pk;
      }
    }
    // PV: O[q][d] (64x32, K=64)
#pragma unroll
    for (int i = 0; i < 8; ++i) o[hh][i] = (f32x4){0.f, 0.f, 0.f, 0.f};
#pragma unroll
    for (int ks = 0; ks < 2; ++ks) {
      short8 pa[4], vb[2];
#pragma unroll
      for (int mf = 0; mf < 4; ++mf)
        pa[mf] = *(const short8*)(PP + (mf * 16 + l15) * 72 + ks * 32 + kk8);
#pragma unroll
      for (int nf = 0; nf < 2; ++nf)
        vb[nf] = *(const short8*)(VT8 + h * 2304 + (nf * 16 + l15) * 72 + ks * 32 + kk8);
#pragma unroll
      for (int mf = 0; mf < 4; ++mf)
#pragma unroll
        for (int nf = 0; nf < 2; ++nf)
          o[hh][mf * 2 + nf] = __builtin_amdgcn_mfma_f32_16x16x32_bf16(pa[mf], vb[nf], o[hh][mf * 2 + nf], 0, 0, 0);
    }
  }
  __syncthreads();   // all waves done with VT8/PP
  // O -> OB bf16
#pragma unroll
  for (int hh = 0; hh < 2; ++hh) {
    int h = w + hh * 4;
#pragma unroll
    for (int mf = 0; mf < 4; ++mf)
#pragma unroll
      for (int nf = 0; nf < 2; ++nf)
#pragma unroll
        for (int j = 0; j < 4; ++j) {
          int row = mf * 16 + rj + j;
          int col = h * 32 + nf * 16 + l15;
          OB[row * 264 + col] = f2b(o[hh][mf * 2 + nf][j]);
        }
  }

  // proj GEMM (64x256, K=256, BK=64)
  const int wm = w >> 1, wn = w & 1;
  f32x4 acc[2][8];
#pragma unroll
  for (int mf = 0; mf < 2; ++mf)
#pragma unroll
    for (int nf = 0; nf < 8; ++nf) acc[mf][nf] = (f32x4){0.f, 0.f, 0.f, 0.f};
  for (int kb = 0; kb < 4; ++kb) {
    __syncthreads();
    {
      const unsigned short* src = wproj + (size_t)t * 256 + kb * 64;
#pragma unroll
      for (int c = 0; c < 8; ++c)
        *(int4*)((char*)BSp + t * 144 + c * 16) = *(const int4*)(src + c * 8);
    }
    __syncthreads();
#pragma unroll
    for (int ks = 0; ks < 2; ++ks) {
      short8 a_[2], b_[8];
      int ko = kb * 64 + ks * 32 + kk8;
#pragma unroll
      for (int mf = 0; mf < 2; ++mf)
        a_[mf] = *(const short8*)((char*)OB + (wm * 32 + mf * 16 + l15) * 528 + ko * 2);
#pragma unroll
      for (int nf = 0; nf < 8; ++nf)
        b_[nf] = *(const short8*)((char*)BSp + (wn * 128 + nf * 16 + l15) * 144 + (ks * 32 + kk8) * 2);
#pragma unroll
      for (int mf = 0; mf < 2; ++mf)
#pragma unroll
        for (int nf = 0; nf < 8; ++nf)
          acc[mf][nf] = __builtin_amdgcn_mfma_f32_16x16x32_bf16(a_[mf], b_[nf], acc[mf][nf], 0, 0, 0);
    }
  }
  __syncthreads();
#pragma unroll
  for (int mf = 0; mf < 2; ++mf)
#pragma unroll
    for (int nf = 0; nf < 8; ++nf)
#pragma unroll
      for (int j = 0; j < 4; ++j) {
        int row = wm * 32 + mf * 16 + rj + j;
        int col = wn * 128 + nf * 16 + l15;
        PR[row * 260 + col] = acc[mf][nf][j] + proj_b[col];
      }
  __syncthreads();
  // LN + shortcut + unshift scatter
  {
    int row = t >> 2, sub = t & 3;
    if (row < 49) {
      float s = 0.f, s2 = 0.f;
      for (int i = 0; i < 16; ++i) {
        int c = sub * 4 + i * 16;
        float4 pv = *(float4*)(PR + row * 260 + c);
        s += pv.x + pv.y + pv.z + pv.w;
        s2 += pv.x * pv.x + pv.y * pv.y + pv.z * pv.z + pv.w * pv.w;
      }
      s += __shfl_xor(s, 1); s += __shfl_xor(s, 2);
      s2 += __shfl_xor(s2, 1); s2 += __shfl_xor(s2, 2);
      float mu = s * (1.0f / 256.0f);
      float var = s2 * (1.0f / 256.0f) - mu * mu;
      float rs = rsqrtf(var + 1e-5f);
      int i2 = row / 7, j2 = row % 7;
      int ho = (wi * 7 + i2 + 3) % 56, wo = (wj * 7 + j2 + 3) % 56;
      size_t base = (size_t)(b * 3136 + ho * 56 + wo) * 256;
      for (int i = 0; i < 16; ++i) {
        int c = sub * 4 + i * 16;
        float4 pv = *(float4*)(PR + row * 260 + c);
        float4 xv = *(const float4*)(x + base + c);
        float4 oo;
        oo.x = xv.x + (pv.x - mu) * rs * n1w[c + 0] + n1b[c + 0];
        oo.y = xv.y + (pv.y - mu) * rs * n1w[c + 1] + n1b[c + 1];
        oo.z = xv.z + (pv.z - mu) * rs * n1w[c + 2] + n1b[c + 2];
        oo.w = xv.w + (pv.w - mu) * rs * n1w[c + 3] + n1b[c + 3];
        *(float4*)(x1 + base + c) = oo;
      }
    }
  }
}

// ---------------- k_fc1: H = gelu(x1 @ W1^T + b1), 128x128 tile ----------------
__launch_bounds__(256)
__global__ void k_fc1(const float* __restrict__ x1, const unsigned short* __restrict__ w1,
                      const float* __restrict__ b1, unsigned short* __restrict__ Hbuf, int r0) {
  const int mb = blockIdx.x, nb = blockIdx.y;
  const int t = threadIdx.x, lane = t & 63, w = t >> 6;
  const int wm = w >> 1, wn = w & 1;
  const int l15 = lane & 15, kk8 = (lane >> 4) << 3, rj = (lane >> 4) << 2;

  __shared__ __align__(16) char smem[36864];
  unsigned short* As = (unsigned short*)smem;            // [128][72]
  unsigned short* Bs = (unsigned short*)(smem + 18432);  // [128][72]

  f32x4 acc[4][4];
#pragma unroll
  for (int mf = 0; mf < 4; ++mf)
#pragma unroll
    for (int nf = 0; nf < 4; ++nf) acc[mf][nf] = (f32x4){0.f, 0.f, 0.f, 0.f};

  const int row_g0 = r0 + mb * 128;
  const int srow = t >> 1, sh = t & 1;

  for (int kb = 0; kb < 4; ++kb) {
    __syncthreads();
    {
      const float* src = x1 + (size_t)(row_g0 + srow) * 256 + kb * 64 + sh * 32;
#pragma unroll
      for (int c = 0; c < 4; ++c) {
        float4 f0 = *(const float4*)(src + c * 8);
        float4 f1 = *(const float4*)(src + c * 8 + 4);
        int4 pk;
        pk.x = (unsigned)f2b(f0.x) | ((unsigned)f2b(f0.y) << 16);
        pk.y = (unsigned)f2b(f0.z) | ((unsigned)f2b(f0.w) << 16);
        pk.z = (unsigned)f2b(f1.x) | ((unsigned)f2b(f1.y) << 16);
        pk.w = (unsigned)f2b(f1.z) | ((unsigned)f2b(f1.w) << 16);
        *(int4*)((char*)As + srow * 144 + sh * 64 + c * 16) = pk;
      }
      const unsigned short* srcb = w1 + (size_t)(nb * 128 + srow) * 256 + kb * 64 + sh * 32;
#pragma unroll
      for (int c = 0; c < 4; ++c)
        *(int4*)((char*)Bs + srow * 144 + sh * 64 + c * 16) = *(const int4*)(srcb + c * 8);
    }
    __syncthreads();
#pragma unroll
    for (int ks = 0; ks < 2; ++ks) {
      int ko = ks * 32 + kk8;
      short8 a_[4], b_[4];
#pragma unroll
      for (int mf = 0; mf < 4; ++mf)
        a_[mf] = *(const short8*)((char*)As + (wm * 64 + mf * 16 + l15) * 144 + ko * 2);
#pragma unroll
      for (int nf = 0; nf < 4; ++nf)
        b_[nf] = *(const short8*)((char*)Bs + (wn * 64 + nf * 16 + l15) * 144 + ko * 2);
#pragma unroll
      for (int mf = 0; mf < 4; ++mf)
#pragma unroll
        for (int nf = 0; nf < 4; ++nf)
          acc[mf][nf] = __builtin_amdgcn_mfma_f32_16x16x32_bf16(a_[mf], b_[nf], acc[mf][nf], 0, 0, 0);
    }
  }
#pragma unroll
  for (int mf = 0; mf < 4; ++mf)
#pragma unroll
    for (int nf = 0; nf < 4; ++nf) {
      int col = nb * 128 + wn * 64 + nf * 16 + l15;
      float bias = b1[col];
#pragma unroll
      for (int j = 0; j < 4; ++j) {
        int row = mb * 128 + wm * 64 + mf * 16 + rj + j;
        Hbuf[(size_t)row * 1024 + col] = f2b(gelu_tanh(acc[mf][nf][j] + bias));
      }
    }
}

// ---------------- k_fc2: out = x1 + LN(H @ W2^T + b2), 64x256 tile, wave-local LN ----------------
__launch_bounds__(256)
__global__ void k_fc2(const unsigned short* __restrict__ Hbuf, const unsigned short* __restrict__ w2,
                      const float* __restrict__ b2, const float* __restrict__ n2w,
                      const float* __restrict__ n2b, float* __restrict__ xio, int r0) {
  const int mb = blockIdx.x;
  const int t = threadIdx.x, lane = t & 63, w = t >> 6;
  const int l15 = lane & 15, g = lane >> 4, kk8 = g << 3, rj = g << 2;

  __shared__ __align__(16) char smem[46080];
  unsigned short* As = (unsigned short*)smem;           // [64][72]
  unsigned short* Bs = (unsigned short*)(smem + 9216);  // [256][72]

  f32x4 acc[16];
#pragma unroll
  for (int nf = 0; nf < 16; ++nf) acc[nf] = (f32x4){0.f, 0.f, 0.f, 0.f};

  for (int kb = 0; kb < 16; ++kb) {
    __syncthreads();
    {
      int ar = t >> 2, aq = t & 3;
      const unsigned short* sa = Hbuf + (size_t)(mb * 64 + ar) * 1024 + kb * 64 + aq * 16;
      *(int4*)((char*)As + ar * 144 + aq * 32) = *(const int4*)sa;
      *(int4*)((char*)As + ar * 144 + aq * 32 + 16) = *(const int4*)(sa + 8);
      const unsigned short* sb = w2 + (size_t)t * 1024 + kb * 64;
#pragma unroll
      for (int c = 0; c < 8; ++c)
        *(int4*)((char*)Bs + t * 144 + c * 16) = *(const int4*)(sb + c * 8);
    }
    __syncthreads();
#pragma unroll
    for (int ks = 0; ks < 2; ++ks) {
      short8 a_ = *(const short8*)((char*)As + (w * 16 + l15) * 144 + (ks * 32 + kk8) * 2);
      short8 b_[16];
#pragma unroll
      for (int nf = 0; nf < 16; ++nf)
        b_[nf] = *(const short8*)((char*)Bs + (nf * 16 + l15) * 144 + (ks * 32 + kk8) * 2);
#pragma unroll
      for (int nf = 0; nf < 16; ++nf)
        acc[nf] = __builtin_amdgcn_mfma_f32_16x16x32_bf16(a_, b_[nf], acc[nf], 0, 0, 0);
    }
  }
#pragma unroll
  for (int nf = 0; nf < 16; ++nf) {
    float bias = b2[nf * 16 + l15];
#pragma unroll
    for (int j = 0; j < 4; ++j) acc[nf][j] += bias;
  }
#pragma unroll
  for (int j = 0; j < 4; ++j) {
    float s = 0.f, s2 = 0.f;
#pragma unroll
    for (int nf = 0; nf < 16; ++nf) {
      float v = acc[nf][j];
      s += v; s2 += v * v;
    }
    s += __shfl_xor(s, 1);  s += __shfl_xor(s, 2);  s += __shfl_xor(s, 4);  s += __shfl_xor(s, 8);
    s2 += __shfl_xor(s2, 1); s2 += __shfl_xor(s2, 2); s2 += __shfl_xor(s2, 4); s2 += __shfl_xor(s2, 8);
    float mu = s * (1.0f / 256.0f);
    float var = s2 * (1.0f / 256.0f) - mu * mu;
    float rs = rsqrtf(var + 1e-5f);
    size_t base = (size_t)(r0 + mb * 64 + w * 16 + rj + j) * 256;
#pragma unroll
    for (int nf = 0; nf < 16; ++nf) {
      int col = nf * 16 + l15;
      float xv = xio[base + col];
      xio[base + col] = xv + (acc[nf][j] - mu) * rs * n2w[col] + n2b[col];
    }
  }
}

extern "C" void kernel_launch(void* const* d_in, const int* in_sizes, int n_in,
                              void* d_out, int out_size, void* d_ws, size_t ws_size,
                              hipStream_t stream) {
  const float* x           = (const float*)d_in[0];
  const float* norm1_w     = (const float*)d_in[1];
  const float* norm1_b     = (const float*)d_in[2];
  const float* qkv_w       = (const float*)d_in[3];
  const float* q_bias      = (const float*)d_in[4];
  const float* v_bias      = (const float*)d_in[5];
  const float* logit_scale = (const float*)d_in[6];
  const float* cpb_w1      = (const float*)d_in[7];
  const float* cpb_b1      = (const float*)d_in[8];
  const float* cpb_w2      = (const float*)d_in[9];
  const float* proj_w      = (const float*)d_in[10];
  const float* proj_b      = (const float*)d_in[11];
  const float* norm2_w     = (const float*)d_in[12];
  const float* norm2_b     = (const float*)d_in[13];
  const float* fc1_w       = (const float*)d_in[14];
  const float* fc1_b       = (const float*)d_in[15];
  const float* fc2_w       = (const float*)d_in[16];
  const float* fc2_b       = (const float*)d_in[17];

  char* ws = (char*)d_ws;
  float*          scales  = (float*)(ws + 0);
  float*          tblg    = (float*)(ws + 64);
  unsigned short* wq      = (unsigned short*)(ws + 8192);    // 393216 B; biasT overlays after k_qkv
  float*          biasT   = (float*)(ws + 8192);             // 131072 B (written by k_bias)
  unsigned short* wp      = (unsigned short*)(ws + 401408);
  unsigned short* w1b     = (unsigned short*)(ws + 532480);
  unsigned short* w2b     = (unsigned short*)(ws + 1056768);
  unsigned short* qkvbuf  = (unsigned short*)(ws + 1581056); // 77070336 B
  unsigned short* Hbuf    = (unsigned short*)(ws + 1581056); // reuses qkvbuf region
  float*          x1      = (float*)d_out;

  k_misc<<<dim3(1), dim3(256), 0, stream>>>(logit_scale, cpb_w1, cpb_b1, cpb_w2, scales, tblg);
  k_cvt<<<dim3(3072), dim3(256), 0, stream>>>(qkv_w, proj_w, fc1_w, fc2_w, wq, wp, w1b, w2b);
  k_qkv<<<dim3(3072), dim3(256), 0, stream>>>(x, wq, q_bias, v_bias, scales, qkvbuf);
  k_bias<<<dim3(128), dim3(256), 0, stream>>>(tblg, biasT);
  k_attn<<<dim3(1024), dim3(256), 0, stream>>>(x, qkvbuf, wp, proj_b, norm1_w, norm1_b, biasT, x1);
  k_fc1<<<dim3(196, 8), dim3(256), 0, stream>>>(x1, w1b, fc1_b, Hbuf, 0);
  k_fc2<<<dim3(392), dim3(256), 0, stream>>>(Hbuf, w2b, fc2_b, norm2_w, norm2_b, x1, 0);
  k_fc1<<<dim3(196, 8), dim3(256), 0, stream>>>(x1, w1b, fc1_b, Hbuf, 25088);
  k_fc2<<<dim3(392), dim3(256), 0, stream>>>(Hbuf, w2b, fc2_b, norm2_w, norm2_b, x1, 25088);
}

// Round 6
// 481.168 us; speedup vs baseline: 1.3012x; 1.1186x over previous
//
#include <hip/hip_runtime.h>

typedef __attribute__((ext_vector_type(8))) short short8;
typedef __attribute__((ext_vector_type(4))) float f32x4;

__device__ __forceinline__ unsigned short f2b(float f) {
  unsigned u = __float_as_uint(f);
  return (unsigned short)((u + 0x7FFFu + ((u >> 16) & 1u)) >> 16);
}
__device__ __forceinline__ float b2f(unsigned short h) {
  return __uint_as_float(((unsigned)h) << 16);
}
__device__ __forceinline__ float gelu_tanh(float v) {
  float c = 0.7978845608028654f * (v + 0.044715f * v * v * v);
  return 0.5f * v * (1.0f + tanhf(c));
}

// ---------------- k_misc: scales + CPB table (raw, per rel-coord) ----------------
__global__ void k_misc(const float* __restrict__ logit_scale,
                       const float* __restrict__ w1, const float* __restrict__ b1,
                       const float* __restrict__ w2,
                       float* __restrict__ scales, float* __restrict__ tblg) {
  int t = threadIdx.x;
  if (t < 8) scales[t] = expf(fminf(logit_scale[t], logf(100.0f)));
  if (t < 169) {
    int a = t / 13, b = t % 13;
    float ra = (float)(a - 6) * (8.0f / 6.0f);
    float rb = (float)(b - 6) * (8.0f / 6.0f);
    float sa = (ra > 0.f) ? 1.f : ((ra < 0.f) ? -1.f : 0.f);
    float sb = (rb > 0.f) ? 1.f : ((rb < 0.f) ? -1.f : 0.f);
    float t0 = sa * log2f(fabsf(ra) + 1.0f) / 3.0f;
    float t1 = sb * log2f(fabsf(rb) + 1.0f) / 3.0f;
    float acc[8];
#pragma unroll
    for (int hh = 0; hh < 8; ++hh) acc[hh] = 0.f;
    for (int j = 0; j < 512; ++j) {
      float hv = fmaxf(w1[2*j] * t0 + w1[2*j+1] * t1 + b1[j], 0.0f);
#pragma unroll
      for (int hh = 0; hh < 8; ++hh) acc[hh] += w2[hh*512 + j] * hv;
    }
#pragma unroll
    for (int hh = 0; hh < 8; ++hh) tblg[t * 8 + hh] = acc[hh];
  }
}

// ---------------- k_bias: biasT[h][k][q] padded 64x64, pad=-3e8 ----------------
__global__ void k_bias(const float* __restrict__ tblg, float* __restrict__ biasT) {
  int idx = blockIdx.x * 256 + threadIdx.x;   // 8*64*64 = 32768
  int h = idx >> 12, rem = idx & 4095, k = rem >> 6, q = rem & 63;
  float v;
  if (k >= 49 || q >= 49) {
    v = -3.0e8f;
  } else {
    int e = (q / 7 - k / 7 + 6) * 13 + (q % 7 - k % 7 + 6);
    float r = tblg[e * 8 + h];
    v = 16.0f / (1.0f + expf(-r));
  }
  biasT[idx] = v;
}

// ---------------- k_cvt: weights fp32 -> bf16 ----------------
__global__ void k_cvt(const float* __restrict__ qkv_w, const float* __restrict__ proj_w,
                      const float* __restrict__ fc1_w, const float* __restrict__ fc2_w,
                      unsigned short* __restrict__ wq, unsigned short* __restrict__ wp,
                      unsigned short* __restrict__ w1, unsigned short* __restrict__ w2) {
  int i = blockIdx.x * 256 + threadIdx.x;
  if (i < 196608) wq[i] = f2b(qkv_w[i]);
  else if (i < 262144) wp[i - 196608] = f2b(proj_w[i - 196608]);
  else if (i < 524288) w1[i - 262144] = f2b(fc1_w[i - 262144]);
  else w2[i - 524288] = f2b(fc2_w[i - 524288]);
}

// ---------------- k_xprep: shifted-window gather x -> xw[50176][256] bf16 ----------------
__global__ void k_xprep(const float* __restrict__ x, unsigned short* __restrict__ xw) {
  int id = blockIdx.x * 256 + threadIdx.x;   // 50176*32 threads, 8 elems each
  int row = id >> 5, c8 = (id & 31) << 3;
  int win = row / 49, r = row - win * 49;
  int b = win >> 6, wi = (win >> 3) & 7, wj = win & 7;
  int i = r / 7, j = r - i * 7;
  int ho = (wi * 7 + i + 3) % 56;
  int wo = (wj * 7 + j + 3) % 56;
  const float* src = x + (size_t)(b * 3136 + ho * 56 + wo) * 256 + c8;
  float4 f0 = *(const float4*)(src);
  float4 f1 = *(const float4*)(src + 4);
  int4 pk;
  pk.x = (unsigned)f2b(f0.x) | ((unsigned)f2b(f0.y) << 16);
  pk.y = (unsigned)f2b(f0.z) | ((unsigned)f2b(f0.w) << 16);
  pk.z = (unsigned)f2b(f1.x) | ((unsigned)f2b(f1.y) << 16);
  pk.w = (unsigned)f2b(f1.z) | ((unsigned)f2b(f1.w) << 16);
  *(int4*)(xw + (size_t)row * 256 + c8) = pk;
}

// ---------------- k_qkvg: dense QKV GEMM 50176x768x256 + fused q/k norm ----------------
__launch_bounds__(256)
__global__ void k_qkvg(const unsigned short* __restrict__ xw, const unsigned short* __restrict__ wq,
                       const float* __restrict__ q_bias, const float* __restrict__ v_bias,
                       const float* __restrict__ scales, unsigned short* __restrict__ qkv) {
  const int mb = blockIdx.x, nb = blockIdx.y;   // 392 x 6
  const int t = threadIdx.x, lane = t & 63, w = t >> 6;
  const int wm = w >> 1, wn = w & 1;
  const int l15 = lane & 15, kk8 = (lane >> 4) << 3, rj = (lane >> 4) << 2;

  __shared__ __align__(16) char smem[36864];
  unsigned short* As = (unsigned short*)smem;            // [128][72]
  unsigned short* Bs = (unsigned short*)(smem + 18432);  // [128][72]

  f32x4 acc[4][4];
#pragma unroll
  for (int mf = 0; mf < 4; ++mf)
#pragma unroll
    for (int nf = 0; nf < 4; ++nf) acc[mf][nf] = (f32x4){0.f, 0.f, 0.f, 0.f};

  const int srow = t >> 1, sh = t & 1;
  for (int kb = 0; kb < 4; ++kb) {
    __syncthreads();
    {
      const unsigned short* sa = xw + (size_t)(mb * 128 + srow) * 256 + kb * 64 + sh * 32;
#pragma unroll
      for (int c = 0; c < 4; ++c)
        *(int4*)((char*)As + srow * 144 + sh * 64 + c * 16) = *(const int4*)(sa + c * 8);
      const unsigned short* sb = wq + (size_t)(nb * 128 + srow) * 256 + kb * 64 + sh * 32;
#pragma unroll
      for (int c = 0; c < 4; ++c)
        *(int4*)((char*)Bs + srow * 144 + sh * 64 + c * 16) = *(const int4*)(sb + c * 8);
    }
    __syncthreads();
#pragma unroll
    for (int ks = 0; ks < 2; ++ks) {
      int ko = ks * 32 + kk8;
      short8 a_[4], b_[4];
#pragma unroll
      for (int mf = 0; mf < 4; ++mf)
        a_[mf] = *(const short8*)((char*)As + (wm * 64 + mf * 16 + l15) * 144 + ko * 2);
#pragma unroll
      for (int nf = 0; nf < 4; ++nf)
        b_[nf] = *(const short8*)((char*)Bs + (wn * 64 + nf * 16 + l15) * 144 + ko * 2);
#pragma unroll
      for (int mf = 0; mf < 4; ++mf)
#pragma unroll
        for (int nf = 0; nf < 4; ++nf)
          acc[mf][nf] = __builtin_amdgcn_mfma_f32_16x16x32_bf16(a_[mf], b_[nf], acc[mf][nf], 0, 0, 0);
    }
  }

  const int which = nb >> 1;
  // bias add (q/v)
  if (which != 1) {
    const float* bp = (which == 0) ? q_bias : v_bias;
#pragma unroll
    for (int nf = 0; nf < 4; ++nf) {
      float bias = bp[(nb & 1) * 128 + wn * 64 + nf * 16 + l15];
#pragma unroll
      for (int mf = 0; mf < 4; ++mf)
#pragma unroll
        for (int j = 0; j < 4; ++j) acc[mf][nf][j] += bias;
    }
  }
  // q/k per-row L2-normalize over head's 32 cols (frag pairs), fold scale into q
  if (which < 2) {
#pragma unroll
    for (int mf = 0; mf < 4; ++mf)
#pragma unroll
      for (int p = 0; p < 2; ++p)
#pragma unroll
        for (int j = 0; j < 4; ++j) {
          float ss = acc[mf][2*p][j] * acc[mf][2*p][j] + acc[mf][2*p+1][j] * acc[mf][2*p+1][j];
          ss += __shfl_xor(ss, 1); ss += __shfl_xor(ss, 2);
          ss += __shfl_xor(ss, 4); ss += __shfl_xor(ss, 8);
          float inv = 1.0f / fmaxf(sqrtf(ss), 1e-12f);
          if (which == 0) inv *= scales[(nb & 1) * 4 + wn * 2 + p];
          acc[mf][2*p][j] *= inv;
          acc[mf][2*p+1][j] *= inv;
        }
  }
  // scatter to [win][3][head][49][32]
  const int head = (nb & 1) * 4 + wn * 2;
#pragma unroll
  for (int mf = 0; mf < 4; ++mf)
#pragma unroll
    for (int j = 0; j < 4; ++j) {
      int row_g = mb * 128 + wm * 64 + mf * 16 + rj + j;
      int win = row_g / 49, r = row_g - win * 49;
      size_t base = (((size_t)win * 3 + which) * 8) * 1568;   // *49*32
#pragma unroll
      for (int nf = 0; nf < 4; ++nf) {
        int h = head + (nf >> 1), d = (nf & 1) * 16 + l15;
        qkv[base + (size_t)h * 1568 + r * 32 + d] = f2b(acc[mf][nf][j]);
      }
    }
}

// ---------------- k_attn: swapped-QK^T per-wave attention + proj + LN ----------------
__launch_bounds__(256)
__global__ void k_attn(const float* __restrict__ x, const unsigned short* __restrict__ qkv,
                       const unsigned short* __restrict__ wproj, const float* __restrict__ proj_b,
                       const float* __restrict__ n1w, const float* __restrict__ n1b,
                       const float* __restrict__ biasT, float* __restrict__ x1) {
  const int win = blockIdx.x;
  const int b = win >> 6, wi = (win >> 3) & 7, wj = win & 7;
  const int t = threadIdx.x, lane = t & 63, w = t >> 6;
  const int l15 = lane & 15, g = lane >> 4;
  const int kk8 = g << 3, rj = g << 2;

  __shared__ __align__(16) char smem[73728];
  unsigned short* VT8 = (unsigned short*)smem;                        // [8][32][72]
  unsigned short* PP  = (unsigned short*)(smem + 36864) + w * 4608;   // per-wave [64][72]
  unsigned short* OB  = (unsigned short*)smem;                        // alias: [64][264]
  unsigned short* BSp = (unsigned short*)(smem + 36864);              // alias: [256][72]
  float*          PR  = (float*)smem;                                 // alias: [64][260]

  const int vi = (wi == 7) ? 1 : 0, vj = (wj == 7) ? 1 : 0;

  // stage V transposed for all 8 heads; zero-pad k=49..63
  for (int idx = t; idx < 392; idx += 256) {
    int h = idx / 49, r = idx % 49;
    const unsigned short* vp = qkv + ((((size_t)win * 3 + 2) * 8 + h) * 49 + r) * 32;
    unsigned short vv[32];
    *(int4*)(vv + 0)  = *(const int4*)(vp + 0);
    *(int4*)(vv + 8)  = *(const int4*)(vp + 8);
    *(int4*)(vv + 16) = *(const int4*)(vp + 16);
    *(int4*)(vv + 24) = *(const int4*)(vp + 24);
    unsigned short* dst = VT8 + h * 2304;
#pragma unroll
    for (int d = 0; d < 32; ++d) dst[d * 72 + r] = vv[d];
  }
  for (int idx = t; idx < 3840; idx += 256) {
    int h = idx / 480, rem = idx % 480, d = rem / 15, r = 49 + rem % 15;
    VT8[h * 2304 + d * 72 + r] = 0;
  }
  __syncthreads();

  f32x4 o[2][8];
  for (int hh = 0; hh < 2; ++hh) {
    const int h = w + hh * 4;
    const float* bT = biasT + (size_t)h * 4096;
    f32x4 s[4][4];
#pragma unroll
    for (int mf = 0; mf < 4; ++mf)
#pragma unroll
      for (int nf = 0; nf < 4; ++nf)
#pragma unroll
        for (int j = 0; j < 4; ++j)
          s[mf][nf][j] = bT[(mf * 16 + rj + j) * 64 + nf * 16 + l15];
    if (vi | vj) {
      int rq[4];
#pragma unroll
      for (int nf = 0; nf < 4; ++nf) {
        int q = nf * 16 + l15, qi = q / 7, qj = q - qi * 7;
        int aq = vi ? (qi < 4 ? 1 : 2) : 0;
        int bq = vj ? (qj < 4 ? 1 : 2) : 0;
        rq[nf] = aq * 3 + bq;
      }
#pragma unroll
      for (int mf = 0; mf < 4; ++mf)
#pragma unroll
        for (int j = 0; j < 4; ++j) {
          int k = mf * 16 + rj + j, ki = k / 7, kj = k - ki * 7;
          int ak = vi ? (ki < 4 ? 1 : 2) : 0;
          int bk = vj ? (kj < 4 ? 1 : 2) : 0;
          int rk = ak * 3 + bk;
#pragma unroll
          for (int nf = 0; nf < 4; ++nf)
            if (rq[nf] != rk) s[mf][nf][j] -= 100.0f;
        }
    }
    const unsigned short* kp = qkv + (((size_t)win * 3 + 1) * 8 + h) * 1568;
    const unsigned short* qp = qkv + (((size_t)win * 3 + 0) * 8 + h) * 1568;
    short8 ka[4], qa[4];
#pragma unroll
    for (int f = 0; f < 4; ++f) {
      ka[f] = *(const short8*)(kp + (f * 16 + l15) * 32 + kk8);
      qa[f] = *(const short8*)(qp + (f * 16 + l15) * 32 + kk8);
    }
#pragma unroll
    for (int mf = 0; mf < 4; ++mf)
#pragma unroll
      for (int nf = 0; nf < 4; ++nf)
        s[mf][nf] = __builtin_amdgcn_mfma_f32_16x16x32_bf16(ka[mf], qa[nf], s[mf][nf], 0, 0, 0);

#pragma unroll
    for (int nf = 0; nf < 4; ++nf) {
      float m = -3.0e8f;
#pragma unroll
      for (int mf = 0; mf < 4; ++mf)
#pragma unroll
        for (int j = 0; j < 4; ++j) m = fmaxf(m, s[mf][nf][j]);
      m = fmaxf(m, __shfl_xor(m, 16));
      m = fmaxf(m, __shfl_xor(m, 32));
      float sum = 0.f;
#pragma unroll
      for (int mf = 0; mf < 4; ++mf)
#pragma unroll
        for (int j = 0; j < 4; ++j) {
          float e = __expf(s[mf][nf][j] - m);
          s[mf][nf][j] = e; sum += e;
        }
      sum += __shfl_xor(sum, 16);
      sum += __shfl_xor(sum, 32);
      float inv = 1.0f / sum;
      unsigned short* pq = PP + (nf * 16 + l15) * 72;
#pragma unroll
      for (int mf = 0; mf < 4; ++mf) {
        int2 pk;
        pk.x = (int)((unsigned)f2b(s[mf][nf][0] * inv) | ((unsigned)f2b(s[mf][nf][1] * inv) << 16));
        pk.y = (int)((unsigned)f2b(s[mf][nf][2] * inv) | ((unsigned)f2b(s[mf][nf][3] * inv) << 16));
        *(int2*)(pq + mf * 16 + rj) = pk;
      }
    }
#pragma unroll
    for (int i = 0; i < 8; ++i) o[hh][i] = (f32x4){0.f, 0.f, 0.f, 0.f};
#pragma unroll
    for (int ks = 0; ks < 2; ++ks) {
      short8 pa[4], vb[2];
#pragma unroll
      for (int mf = 0; mf < 4; ++mf)
        pa[mf] = *(const short8*)(PP + (mf * 16 + l15) * 72 + ks * 32 + kk8);
#pragma unroll
      for (int nf = 0; nf < 2; ++nf)
        vb[nf] = *(const short8*)(VT8 + h * 2304 + (nf * 16 + l15) * 72 + ks * 32 + kk8);
#pragma unroll
      for (int mf = 0; mf < 4; ++mf)
#pragma unroll
        for (int nf = 0; nf < 2; ++nf)
          o[hh][mf * 2 + nf] = __builtin_amdgcn_mfma_f32_16x16x32_bf16(pa[mf], vb[nf], o[hh][mf * 2 + nf], 0, 0, 0);
    }
  }
  __syncthreads();
#pragma unroll
  for (int hh = 0; hh < 2; ++hh) {
    int h = w + hh * 4;
#pragma unroll
    for (int mf = 0; mf < 4; ++mf)
#pragma unroll
      for (int nf = 0; nf < 2; ++nf)
#pragma unroll
        for (int j = 0; j < 4; ++j) {
          int row = mf * 16 + rj + j;
          int col = h * 32 + nf * 16 + l15;
          OB[row * 264 + col] = f2b(o[hh][mf * 2 + nf][j]);
        }
  }

  const int wm = w >> 1, wn = w & 1;
  f32x4 acc[2][8];
#pragma unroll
  for (int mf = 0; mf < 2; ++mf)
#pragma unroll
    for (int nf = 0; nf < 8; ++nf) acc[mf][nf] = (f32x4){0.f, 0.f, 0.f, 0.f};
  for (int kb = 0; kb < 4; ++kb) {
    __syncthreads();
    {
      const unsigned short* src = wproj + (size_t)t * 256 + kb * 64;
#pragma unroll
      for (int c = 0; c < 8; ++c)
        *(int4*)((char*)BSp + t * 144 + c * 16) = *(const int4*)(src + c * 8);
    }
    __syncthreads();
#pragma unroll
    for (int ks = 0; ks < 2; ++ks) {
      short8 a_[2], b_[8];
      int ko = kb * 64 + ks * 32 + kk8;
#pragma unroll
      for (int mf = 0; mf < 2; ++mf)
        a_[mf] = *(const short8*)((char*)OB + (wm * 32 + mf * 16 + l15) * 528 + ko * 2);
#pragma unroll
      for (int nf = 0; nf < 8; ++nf)
        b_[nf] = *(const short8*)((char*)BSp + (wn * 128 + nf * 16 + l15) * 144 + (ks * 32 + kk8) * 2);
#pragma unroll
      for (int mf = 0; mf < 2; ++mf)
#pragma unroll
        for (int nf = 0; nf < 8; ++nf)
          acc[mf][nf] = __builtin_amdgcn_mfma_f32_16x16x32_bf16(a_[mf], b_[nf], acc[mf][nf], 0, 0, 0);
    }
  }
  __syncthreads();
#pragma unroll
  for (int mf = 0; mf < 2; ++mf)
#pragma unroll
    for (int nf = 0; nf < 8; ++nf)
#pragma unroll
      for (int j = 0; j < 4; ++j) {
        int row = wm * 32 + mf * 16 + rj + j;
        int col = wn * 128 + nf * 16 + l15;
        PR[row * 260 + col] = acc[mf][nf][j] + proj_b[col];
      }
  __syncthreads();
  {
    int row = t >> 2, sub = t & 3;
    if (row < 49) {
      float s = 0.f, s2 = 0.f;
      for (int i = 0; i < 16; ++i) {
        int c = sub * 4 + i * 16;
        float4 pv = *(float4*)(PR + row * 260 + c);
        s += pv.x + pv.y + pv.z + pv.w;
        s2 += pv.x * pv.x + pv.y * pv.y + pv.z * pv.z + pv.w * pv.w;
      }
      s += __shfl_xor(s, 1); s += __shfl_xor(s, 2);
      s2 += __shfl_xor(s2, 1); s2 += __shfl_xor(s2, 2);
      float mu = s * (1.0f / 256.0f);
      float var = s2 * (1.0f / 256.0f) - mu * mu;
      float rs = rsqrtf(var + 1e-5f);
      int i2 = row / 7, j2 = row % 7;
      int ho = (wi * 7 + i2 + 3) % 56, wo = (wj * 7 + j2 + 3) % 56;
      size_t base = (size_t)(b * 3136 + ho * 56 + wo) * 256;
      for (int i = 0; i < 16; ++i) {
        int c = sub * 4 + i * 16;
        float4 pv = *(float4*)(PR + row * 260 + c);
        float4 xv = *(const float4*)(x + base + c);
        float4 oo;
        oo.x = xv.x + (pv.x - mu) * rs * n1w[c + 0] + n1b[c + 0];
        oo.y = xv.y + (pv.y - mu) * rs * n1w[c + 1] + n1b[c + 1];
        oo.z = xv.z + (pv.z - mu) * rs * n1w[c + 2] + n1b[c + 2];
        oo.w = xv.w + (pv.w - mu) * rs * n1w[c + 3] + n1b[c + 3];
        *(float4*)(x1 + base + c) = oo;
      }
    }
  }
}

// ---------------- k_fc1: H = gelu(x1 @ W1^T + b1), 128x128 tile ----------------
__launch_bounds__(256)
__global__ void k_fc1(const float* __restrict__ x1, const unsigned short* __restrict__ w1,
                      const float* __restrict__ b1, unsigned short* __restrict__ Hbuf, int r0) {
  const int mb = blockIdx.x, nb = blockIdx.y;
  const int t = threadIdx.x, lane = t & 63, w = t >> 6;
  const int wm = w >> 1, wn = w & 1;
  const int l15 = lane & 15, kk8 = (lane >> 4) << 3, rj = (lane >> 4) << 2;

  __shared__ __align__(16) char smem[36864];
  unsigned short* As = (unsigned short*)smem;            // [128][72]
  unsigned short* Bs = (unsigned short*)(smem + 18432);  // [128][72]

  f32x4 acc[4][4];
#pragma unroll
  for (int mf = 0; mf < 4; ++mf)
#pragma unroll
    for (int nf = 0; nf < 4; ++nf) acc[mf][nf] = (f32x4){0.f, 0.f, 0.f, 0.f};

  const int row_g0 = r0 + mb * 128;
  const int srow = t >> 1, sh = t & 1;

  for (int kb = 0; kb < 4; ++kb) {
    __syncthreads();
    {
      const float* src = x1 + (size_t)(row_g0 + srow) * 256 + kb * 64 + sh * 32;
#pragma unroll
      for (int c = 0; c < 4; ++c) {
        float4 f0 = *(const float4*)(src + c * 8);
        float4 f1 = *(const float4*)(src + c * 8 + 4);
        int4 pk;
        pk.x = (unsigned)f2b(f0.x) | ((unsigned)f2b(f0.y) << 16);
        pk.y = (unsigned)f2b(f0.z) | ((unsigned)f2b(f0.w) << 16);
        pk.z = (unsigned)f2b(f1.x) | ((unsigned)f2b(f1.y) << 16);
        pk.w = (unsigned)f2b(f1.z) | ((unsigned)f2b(f1.w) << 16);
        *(int4*)((char*)As + srow * 144 + sh * 64 + c * 16) = pk;
      }
      const unsigned short* srcb = w1 + (size_t)(nb * 128 + srow) * 256 + kb * 64 + sh * 32;
#pragma unroll
      for (int c = 0; c < 4; ++c)
        *(int4*)((char*)Bs + srow * 144 + sh * 64 + c * 16) = *(const int4*)(srcb + c * 8);
    }
    __syncthreads();
#pragma unroll
    for (int ks = 0; ks < 2; ++ks) {
      int ko = ks * 32 + kk8;
      short8 a_[4], b_[4];
#pragma unroll
      for (int mf = 0; mf < 4; ++mf)
        a_[mf] = *(const short8*)((char*)As + (wm * 64 + mf * 16 + l15) * 144 + ko * 2);
#pragma unroll
      for (int nf = 0; nf < 4; ++nf)
        b_[nf] = *(const short8*)((char*)Bs + (wn * 64 + nf * 16 + l15) * 144 + ko * 2);
#pragma unroll
      for (int mf = 0; mf < 4; ++mf)
#pragma unroll
        for (int nf = 0; nf < 4; ++nf)
          acc[mf][nf] = __builtin_amdgcn_mfma_f32_16x16x32_bf16(a_[mf], b_[nf], acc[mf][nf], 0, 0, 0);
    }
  }
#pragma unroll
  for (int mf = 0; mf < 4; ++mf)
#pragma unroll
    for (int nf = 0; nf < 4; ++nf) {
      int col = nb * 128 + wn * 64 + nf * 16 + l15;
      float bias = b1[col];
#pragma unroll
      for (int j = 0; j < 4; ++j) {
        int row = mb * 128 + wm * 64 + mf * 16 + rj + j;
        Hbuf[(size_t)row * 1024 + col] = f2b(gelu_tanh(acc[mf][nf][j] + bias));
      }
    }
}

// ---------------- k_fc2: out = x1 + LN(H @ W2^T + b2), 64x256 tile, wave-local LN ----------------
__launch_bounds__(256)
__global__ void k_fc2(const unsigned short* __restrict__ Hbuf, const unsigned short* __restrict__ w2,
                      const float* __restrict__ b2, const float* __restrict__ n2w,
                      const float* __restrict__ n2b, float* __restrict__ xio, int r0) {
  const int mb = blockIdx.x;
  const int t = threadIdx.x, lane = t & 63, w = t >> 6;
  const int l15 = lane & 15, g = lane >> 4, kk8 = g << 3, rj = g << 2;

  __shared__ __align__(16) char smem[46080];
  unsigned short* As = (unsigned short*)smem;           // [64][72]
  unsigned short* Bs = (unsigned short*)(smem + 9216);  // [256][72]

  f32x4 acc[16];
#pragma unroll
  for (int nf = 0; nf < 16; ++nf) acc[nf] = (f32x4){0.f, 0.f, 0.f, 0.f};

  for (int kb = 0; kb < 16; ++kb) {
    __syncthreads();
    {
      int ar = t >> 2, aq = t & 3;
      const unsigned short* sa = Hbuf + (size_t)(mb * 64 + ar) * 1024 + kb * 64 + aq * 16;
      *(int4*)((char*)As + ar * 144 + aq * 32) = *(const int4*)sa;
      *(int4*)((char*)As + ar * 144 + aq * 32 + 16) = *(const int4*)(sa + 8);
      const unsigned short* sb = w2 + (size_t)t * 1024 + kb * 64;
#pragma unroll
      for (int c = 0; c < 8; ++c)
        *(int4*)((char*)Bs + t * 144 + c * 16) = *(const int4*)(sb + c * 8);
    }
    __syncthreads();
#pragma unroll
    for (int ks = 0; ks < 2; ++ks) {
      short8 a_ = *(const short8*)((char*)As + (w * 16 + l15) * 144 + (ks * 32 + kk8) * 2);
      short8 b_[16];
#pragma unroll
      for (int nf = 0; nf < 16; ++nf)
        b_[nf] = *(const short8*)((char*)Bs + (nf * 16 + l15) * 144 + (ks * 32 + kk8) * 2);
#pragma unroll
      for (int nf = 0; nf < 16; ++nf)
        acc[nf] = __builtin_amdgcn_mfma_f32_16x16x32_bf16(a_, b_[nf], acc[nf], 0, 0, 0);
    }
  }
#pragma unroll
  for (int nf = 0; nf < 16; ++nf) {
    float bias = b2[nf * 16 + l15];
#pragma unroll
    for (int j = 0; j < 4; ++j) acc[nf][j] += bias;
  }
#pragma unroll
  for (int j = 0; j < 4; ++j) {
    float s = 0.f, s2 = 0.f;
#pragma unroll
    for (int nf = 0; nf < 16; ++nf) {
      float v = acc[nf][j];
      s += v; s2 += v * v;
    }
    s += __shfl_xor(s, 1);  s += __shfl_xor(s, 2);  s += __shfl_xor(s, 4);  s += __shfl_xor(s, 8);
    s2 += __shfl_xor(s2, 1); s2 += __shfl_xor(s2, 2); s2 += __shfl_xor(s2, 4); s2 += __shfl_xor(s2, 8);
    float mu = s * (1.0f / 256.0f);
    float var = s2 * (1.0f / 256.0f) - mu * mu;
    float rs = rsqrtf(var + 1e-5f);
    size_t base = (size_t)(r0 + mb * 64 + w * 16 + rj + j) * 256;
#pragma unroll
    for (int nf = 0; nf < 16; ++nf) {
      int col = nf * 16 + l15;
      float xv = xio[base + col];
      xio[base + col] = xv + (acc[nf][j] - mu) * rs * n2w[col] + n2b[col];
    }
  }
}

extern "C" void kernel_launch(void* const* d_in, const int* in_sizes, int n_in,
                              void* d_out, int out_size, void* d_ws, size_t ws_size,
                              hipStream_t stream) {
  const float* x           = (const float*)d_in[0];
  const float* norm1_w     = (const float*)d_in[1];
  const float* norm1_b     = (const float*)d_in[2];
  const float* qkv_w       = (const float*)d_in[3];
  const float* q_bias      = (const float*)d_in[4];
  const float* v_bias      = (const float*)d_in[5];
  const float* logit_scale = (const float*)d_in[6];
  const float* cpb_w1      = (const float*)d_in[7];
  const float* cpb_b1      = (const float*)d_in[8];
  const float* cpb_w2      = (const float*)d_in[9];
  const float* proj_w      = (const float*)d_in[10];
  const float* proj_b      = (const float*)d_in[11];
  const float* norm2_w     = (const float*)d_in[12];
  const float* norm2_b     = (const float*)d_in[13];
  const float* fc1_w       = (const float*)d_in[14];
  const float* fc1_b       = (const float*)d_in[15];
  const float* fc2_w       = (const float*)d_in[16];
  const float* fc2_b       = (const float*)d_in[17];

  char* ws = (char*)d_ws;
  float*          scales  = (float*)(ws + 0);
  float*          tblg    = (float*)(ws + 64);
  unsigned short* wq      = (unsigned short*)(ws + 8192);    // 393216 B; biasT overlays after k_qkvg
  float*          biasT   = (float*)(ws + 8192);             // 131072 B (written by k_bias)
  unsigned short* wp      = (unsigned short*)(ws + 401408);
  unsigned short* w1b     = (unsigned short*)(ws + 532480);
  unsigned short* w2b     = (unsigned short*)(ws + 1056768);
  unsigned short* qkvbuf  = (unsigned short*)(ws + 1581056); // 77070336 B
  unsigned short* Hbuf    = (unsigned short*)(ws + 1581056); // reuses qkvbuf region (MLP phase)
  float*          x1      = (float*)d_out;
  // xw (50176x256 bf16 = 25.7 MB) lives in d_out; dead before k_attn overwrites d_out with x1
  unsigned short* xw      = (unsigned short*)d_out;

  k_misc<<<dim3(1), dim3(256), 0, stream>>>(logit_scale, cpb_w1, cpb_b1, cpb_w2, scales, tblg);
  k_cvt<<<dim3(3072), dim3(256), 0, stream>>>(qkv_w, proj_w, fc1_w, fc2_w, wq, wp, w1b, w2b);
  k_xprep<<<dim3(6272), dim3(256), 0, stream>>>(x, xw);
  k_qkvg<<<dim3(392, 6), dim3(256), 0, stream>>>(xw, wq, q_bias, v_bias, scales, qkvbuf);
  k_bias<<<dim3(128), dim3(256), 0, stream>>>(tblg, biasT);
  k_attn<<<dim3(1024), dim3(256), 0, stream>>>(x, qkvbuf, wp, proj_b, norm1_w, norm1_b, biasT, x1);
  k_fc1<<<dim3(196, 8), dim3(256), 0, stream>>>(x1, w1b, fc1_b, Hbuf, 0);
  k_fc2<<<dim3(392), dim3(256), 0, stream>>>(Hbuf, w2b, fc2_b, norm2_w, norm2_b, x1, 0);
  k_fc1<<<dim3(196, 8), dim3(256), 0, stream>>>(x1, w1b, fc1_b, Hbuf, 25088);
  k_fc2<<<dim3(392), dim3(256), 0, stream>>>(Hbuf, w2b, fc2_b, norm2_w, norm2_b, x1, 25088);
}

// Round 7
// 463.444 us; speedup vs baseline: 1.3510x; 1.0382x over previous
//
#include <hip/hip_runtime.h>

typedef __attribute__((ext_vector_type(8))) short short8;
typedef __attribute__((ext_vector_type(4))) float f32x4;

union I4S8 { int4 i; short8 s; };

__device__ __forceinline__ unsigned short f2b(float f) {
  unsigned u = __float_as_uint(f);
  return (unsigned short)((u + 0x7FFFu + ((u >> 16) & 1u)) >> 16);
}
__device__ __forceinline__ unsigned pk2(float a, float b) {
  return (unsigned)f2b(a) | ((unsigned)f2b(b) << 16);
}
__device__ __forceinline__ float b2f(unsigned short h) {
  return __uint_as_float(((unsigned)h) << 16);
}
__device__ __forceinline__ float gelu_tanh(float v) {
  float c = 0.7978845608028654f * (v + 0.044715f * v * v * v);
  return 0.5f * v * (1.0f + tanhf(c));
}

// ---------------- k_misc: scales + CPB table (raw, per rel-coord) ----------------
__global__ void k_misc(const float* __restrict__ logit_scale,
                       const float* __restrict__ w1, const float* __restrict__ b1,
                       const float* __restrict__ w2,
                       float* __restrict__ scales, float* __restrict__ tblg) {
  int t = threadIdx.x;
  if (t < 8) scales[t] = expf(fminf(logit_scale[t], logf(100.0f)));
  if (t < 169) {
    int a = t / 13, b = t % 13;
    float ra = (float)(a - 6) * (8.0f / 6.0f);
    float rb = (float)(b - 6) * (8.0f / 6.0f);
    float sa = (ra > 0.f) ? 1.f : ((ra < 0.f) ? -1.f : 0.f);
    float sb = (rb > 0.f) ? 1.f : ((rb < 0.f) ? -1.f : 0.f);
    float t0 = sa * log2f(fabsf(ra) + 1.0f) / 3.0f;
    float t1 = sb * log2f(fabsf(rb) + 1.0f) / 3.0f;
    float acc[8];
#pragma unroll
    for (int hh = 0; hh < 8; ++hh) acc[hh] = 0.f;
    for (int j = 0; j < 512; ++j) {
      float hv = fmaxf(w1[2*j] * t0 + w1[2*j+1] * t1 + b1[j], 0.0f);
#pragma unroll
      for (int hh = 0; hh < 8; ++hh) acc[hh] += w2[hh*512 + j] * hv;
    }
#pragma unroll
    for (int hh = 0; hh < 8; ++hh) tblg[t * 8 + hh] = acc[hh];
  }
}

// ---------------- k_bias: biasT[h][k][q] padded 64x64, pad=-3e8 ----------------
__global__ void k_bias(const float* __restrict__ tblg, float* __restrict__ biasT) {
  int idx = blockIdx.x * 256 + threadIdx.x;   // 8*64*64 = 32768
  int h = idx >> 12, rem = idx & 4095, k = rem >> 6, q = rem & 63;
  float v;
  if (k >= 49 || q >= 49) {
    v = -3.0e8f;
  } else {
    int e = (q / 7 - k / 7 + 6) * 13 + (q % 7 - k % 7 + 6);
    float r = tblg[e * 8 + h];
    v = 16.0f / (1.0f + expf(-r));
  }
  biasT[idx] = v;
}

// ---------------- k_cvt: weights fp32 -> bf16 ----------------
__global__ void k_cvt(const float* __restrict__ qkv_w, const float* __restrict__ proj_w,
                      const float* __restrict__ fc1_w, const float* __restrict__ fc2_w,
                      unsigned short* __restrict__ wq, unsigned short* __restrict__ wp,
                      unsigned short* __restrict__ w1, unsigned short* __restrict__ w2) {
  int i = blockIdx.x * 256 + threadIdx.x;
  if (i < 196608) wq[i] = f2b(qkv_w[i]);
  else if (i < 262144) wp[i - 196608] = f2b(proj_w[i - 196608]);
  else if (i < 524288) w1[i - 262144] = f2b(fc1_w[i - 262144]);
  else w2[i - 524288] = f2b(fc2_w[i - 524288]);
}

// ---------------- k_xprep: shifted-window gather x -> xw[50176][256] bf16 ----------------
__global__ void k_xprep(const float* __restrict__ x, unsigned short* __restrict__ xw) {
  int id = blockIdx.x * 256 + threadIdx.x;
  int row = id >> 5, c8 = (id & 31) << 3;
  int win = row / 49, r = row - win * 49;
  int b = win >> 6, wi = (win >> 3) & 7, wj = win & 7;
  int i = r / 7, j = r - i * 7;
  int ho = (wi * 7 + i + 3) % 56;
  int wo = (wj * 7 + j + 3) % 56;
  const float* src = x + (size_t)(b * 3136 + ho * 56 + wo) * 256 + c8;
  float4 f0 = *(const float4*)(src);
  float4 f1 = *(const float4*)(src + 4);
  int4 pk;
  pk.x = pk2(f0.x, f0.y);
  pk.y = pk2(f0.z, f0.w);
  pk.z = pk2(f1.x, f1.y);
  pk.w = pk2(f1.z, f1.w);
  *(int4*)(xw + (size_t)row * 256 + c8) = pk;
}

// ---------------- k_qkvg: dense QKV GEMM 50176x768x256 + fused q/k norm ----------------
__launch_bounds__(256)
__global__ void k_qkvg(const unsigned short* __restrict__ xw, const unsigned short* __restrict__ wq,
                       const float* __restrict__ q_bias, const float* __restrict__ v_bias,
                       const float* __restrict__ scales, unsigned short* __restrict__ qkv) {
  const int mb = blockIdx.x, nb = blockIdx.y;   // 392 x 6
  const int t = threadIdx.x, lane = t & 63, w = t >> 6;
  const int wm = w >> 1, wn = w & 1;
  const int l15 = lane & 15, kk8 = (lane >> 4) << 3, rj = (lane >> 4) << 2;

  __shared__ __align__(16) char smem[36864];
  unsigned short* As = (unsigned short*)smem;            // [128][72]
  unsigned short* Bs = (unsigned short*)(smem + 18432);  // [128][72]

  f32x4 acc[4][4];
#pragma unroll
  for (int mf = 0; mf < 4; ++mf)
#pragma unroll
    for (int nf = 0; nf < 4; ++nf) acc[mf][nf] = (f32x4){0.f, 0.f, 0.f, 0.f};

  const int srow = t >> 1, sh = t & 1;
  for (int kb = 0; kb < 4; ++kb) {
    __syncthreads();
    {
      const unsigned short* sa = xw + (size_t)(mb * 128 + srow) * 256 + kb * 64 + sh * 32;
#pragma unroll
      for (int c = 0; c < 4; ++c)
        *(int4*)((char*)As + srow * 144 + sh * 64 + c * 16) = *(const int4*)(sa + c * 8);
      const unsigned short* sb = wq + (size_t)(nb * 128 + srow) * 256 + kb * 64 + sh * 32;
#pragma unroll
      for (int c = 0; c < 4; ++c)
        *(int4*)((char*)Bs + srow * 144 + sh * 64 + c * 16) = *(const int4*)(sb + c * 8);
    }
    __syncthreads();
#pragma unroll
    for (int ks = 0; ks < 2; ++ks) {
      int ko = ks * 32 + kk8;
      short8 a_[4], b_[4];
#pragma unroll
      for (int mf = 0; mf < 4; ++mf)
        a_[mf] = *(const short8*)((char*)As + (wm * 64 + mf * 16 + l15) * 144 + ko * 2);
#pragma unroll
      for (int nf = 0; nf < 4; ++nf)
        b_[nf] = *(const short8*)((char*)Bs + (wn * 64 + nf * 16 + l15) * 144 + ko * 2);
#pragma unroll
      for (int mf = 0; mf < 4; ++mf)
#pragma unroll
        for (int nf = 0; nf < 4; ++nf)
          acc[mf][nf] = __builtin_amdgcn_mfma_f32_16x16x32_bf16(a_[mf], b_[nf], acc[mf][nf], 0, 0, 0);
    }
  }

  const int which = nb >> 1;
  if (which != 1) {
    const float* bp = (which == 0) ? q_bias : v_bias;
#pragma unroll
    for (int nf = 0; nf < 4; ++nf) {
      float bias = bp[(nb & 1) * 128 + wn * 64 + nf * 16 + l15];
#pragma unroll
      for (int mf = 0; mf < 4; ++mf)
#pragma unroll
        for (int j = 0; j < 4; ++j) acc[mf][nf][j] += bias;
    }
  }
  if (which < 2) {
#pragma unroll
    for (int mf = 0; mf < 4; ++mf)
#pragma unroll
      for (int p = 0; p < 2; ++p)
#pragma unroll
        for (int j = 0; j < 4; ++j) {
          float ss = acc[mf][2*p][j] * acc[mf][2*p][j] + acc[mf][2*p+1][j] * acc[mf][2*p+1][j];
          ss += __shfl_xor(ss, 1); ss += __shfl_xor(ss, 2);
          ss += __shfl_xor(ss, 4); ss += __shfl_xor(ss, 8);
          float inv = 1.0f / fmaxf(sqrtf(ss), 1e-12f);
          if (which == 0) inv *= scales[(nb & 1) * 4 + wn * 2 + p];
          acc[mf][2*p][j] *= inv;
          acc[mf][2*p+1][j] *= inv;
        }
  }
  const int head = (nb & 1) * 4 + wn * 2;
#pragma unroll
  for (int mf = 0; mf < 4; ++mf)
#pragma unroll
    for (int j = 0; j < 4; ++j) {
      int row_g = mb * 128 + wm * 64 + mf * 16 + rj + j;
      int win = row_g / 49, r = row_g - win * 49;
      size_t base = (((size_t)win * 3 + which) * 8) * 1568;
#pragma unroll
      for (int nf = 0; nf < 4; ++nf) {
        int h = head + (nf >> 1), d = (nf & 1) * 16 + l15;
        qkv[base + (size_t)h * 1568 + r * 32 + d] = f2b(acc[mf][nf][j]);
      }
    }
}

// ---------------- k_attn2: attention only; O overwrites the q-slice as [49][256] ----------------
__launch_bounds__(256, 3)
__global__ void k_attn2(unsigned short* __restrict__ qkv, const float* __restrict__ biasT) {
  const int win = blockIdx.x;
  const int wi = (win >> 3) & 7, wj = win & 7;
  const int t = threadIdx.x, lane = t & 63, w = t >> 6;
  const int l15 = lane & 15, g = lane >> 4;
  const int kk8 = g << 3, rj = g << 2;

  __shared__ __align__(16) unsigned short VT8[8 * 32 * 72];   // 36864 B

  const int vi = (wi == 7) ? 1 : 0, vj = (wj == 7) ? 1 : 0;

  // stage V transposed for all 8 heads; zero-pad k=49..63
  for (int idx = t; idx < 392; idx += 256) {
    int h = idx / 49, r = idx % 49;
    const unsigned short* vp = qkv + ((((size_t)win * 3 + 2) * 8 + h) * 49 + r) * 32;
    unsigned short vv[32];
    *(int4*)(vv + 0)  = *(const int4*)(vp + 0);
    *(int4*)(vv + 8)  = *(const int4*)(vp + 8);
    *(int4*)(vv + 16) = *(const int4*)(vp + 16);
    *(int4*)(vv + 24) = *(const int4*)(vp + 24);
    unsigned short* dst = VT8 + h * 2304;
#pragma unroll
    for (int d = 0; d < 32; ++d) dst[d * 72 + r] = vv[d];
  }
  for (int idx = t; idx < 3840; idx += 256) {
    int h = idx / 480, rem = idx % 480, d = rem / 15, r = 49 + rem % 15;
    VT8[h * 2304 + d * 72 + r] = 0;
  }
  __syncthreads();

  const int sA = l15 + ((g & 1) << 5);
  const int sB = sA + 16;
  const bool hi = ((g >> 1) & 1) != 0;

  unsigned ob[2][8][2];   // packed bf16 pairs
  for (int hh = 0; hh < 2; ++hh) {
    const int h = w + hh * 4;
    const float* bT = biasT + (size_t)h * 4096;
    f32x4 s[4][4];
#pragma unroll
    for (int mf = 0; mf < 4; ++mf)
#pragma unroll
      for (int nf = 0; nf < 4; ++nf)
#pragma unroll
        for (int j = 0; j < 4; ++j)
          s[mf][nf][j] = bT[(mf * 16 + rj + j) * 64 + nf * 16 + l15];
    if (vi | vj) {
      int rq[4];
#pragma unroll
      for (int nf = 0; nf < 4; ++nf) {
        int q = nf * 16 + l15, qi = q / 7, qj = q - qi * 7;
        int aq = vi ? (qi < 4 ? 1 : 2) : 0;
        int bq = vj ? (qj < 4 ? 1 : 2) : 0;
        rq[nf] = aq * 3 + bq;
      }
#pragma unroll
      for (int mf = 0; mf < 4; ++mf)
#pragma unroll
        for (int j = 0; j < 4; ++j) {
          int k = mf * 16 + rj + j, ki = k / 7, kj = k - ki * 7;
          int ak = vi ? (ki < 4 ? 1 : 2) : 0;
          int bk = vj ? (kj < 4 ? 1 : 2) : 0;
          int rk = ak * 3 + bk;
#pragma unroll
          for (int nf = 0; nf < 4; ++nf)
            if (rq[nf] != rk) s[mf][nf][j] -= 100.0f;
        }
    }
    const unsigned short* kp = qkv + (((size_t)win * 3 + 1) * 8 + h) * 1568;
    const unsigned short* qp = qkv + (((size_t)win * 3 + 0) * 8 + h) * 1568;
    short8 ka[4], qa[4];
#pragma unroll
    for (int f = 0; f < 4; ++f) {
      ka[f] = *(const short8*)(kp + (f * 16 + l15) * 32 + kk8);
      qa[f] = *(const short8*)(qp + (f * 16 + l15) * 32 + kk8);
    }
#pragma unroll
    for (int mf = 0; mf < 4; ++mf)
#pragma unroll
      for (int nf = 0; nf < 4; ++nf)
        s[mf][nf] = __builtin_amdgcn_mfma_f32_16x16x32_bf16(ka[mf], qa[nf], s[mf][nf], 0, 0, 0);

    // softmax over k per q-column (in-lane 16 + xor16 + xor32), normalize in place
    unsigned D[4][4][2];
#pragma unroll
    for (int nf = 0; nf < 4; ++nf) {
      float m = -3.0e8f;
#pragma unroll
      for (int mf = 0; mf < 4; ++mf)
#pragma unroll
        for (int j = 0; j < 4; ++j) m = fmaxf(m, s[mf][nf][j]);
      m = fmaxf(m, __shfl_xor(m, 16));
      m = fmaxf(m, __shfl_xor(m, 32));
      float sum = 0.f;
#pragma unroll
      for (int mf = 0; mf < 4; ++mf)
#pragma unroll
        for (int j = 0; j < 4; ++j) {
          float e = __expf(s[mf][nf][j] - m);
          s[mf][nf][j] = e; sum += e;
        }
      sum += __shfl_xor(sum, 16);
      sum += __shfl_xor(sum, 32);
      float inv = 1.0f / sum;
#pragma unroll
      for (int mf = 0; mf < 4; ++mf) {
        D[mf][nf][0] = pk2(s[mf][nf][0] * inv, s[mf][nf][1] * inv);
        D[mf][nf][1] = pk2(s[mf][nf][2] * inv, s[mf][nf][3] * inv);
      }
    }

    // PV with shfl-assembled A-fragments (no LDS round-trip for P)
    f32x4 o[8];
#pragma unroll
    for (int i = 0; i < 8; ++i) o[i] = (f32x4){0.f, 0.f, 0.f, 0.f};
#pragma unroll
    for (int ks = 0; ks < 2; ++ks) {
      short8 vb[2];
#pragma unroll
      for (int dt = 0; dt < 2; ++dt)
        vb[dt] = *(const short8*)(VT8 + h * 2304 + (dt * 16 + l15) * 72 + ks * 32 + kk8);
#pragma unroll
      for (int qt = 0; qt < 4; ++qt) {
        int a0 = __shfl((int)D[2*ks+0][qt][0], sA), a1 = __shfl((int)D[2*ks+1][qt][0], sA);
        int b0 = __shfl((int)D[2*ks+0][qt][1], sA), b1 = __shfl((int)D[2*ks+1][qt][1], sA);
        int c0 = __shfl((int)D[2*ks+0][qt][0], sB), c1 = __shfl((int)D[2*ks+1][qt][0], sB);
        int e0 = __shfl((int)D[2*ks+0][qt][1], sB), e1 = __shfl((int)D[2*ks+1][qt][1], sB);
        I4S8 u;
        u.i.x = hi ? a1 : a0;
        u.i.y = hi ? b1 : b0;
        u.i.z = hi ? c1 : c0;
        u.i.w = hi ? e1 : e0;
#pragma unroll
        for (int dt = 0; dt < 2; ++dt)
          o[qt * 2 + dt] = __builtin_amdgcn_mfma_f32_16x16x32_bf16(u.s, vb[dt], o[qt * 2 + dt], 0, 0, 0);
      }
    }
#pragma unroll
    for (int f = 0; f < 8; ++f) {
      ob[hh][f][0] = pk2(o[f][0], o[f][1]);
      ob[hh][f][1] = pk2(o[f][2], o[f][3]);
    }
  }
  __syncthreads();   // all Q/K reads complete before overwriting the q-slice

  unsigned short* Ow = qkv + (size_t)win * 37632;   // q-slice viewed as [49][256]
#pragma unroll
  for (int hh = 0; hh < 2; ++hh) {
    int h = w + hh * 4;
#pragma unroll
    for (int qt = 0; qt < 4; ++qt)
#pragma unroll
      for (int j = 0; j < 4; ++j) {
        int q = qt * 16 + rj + j;
        if (q < 49) {
#pragma unroll
          for (int dt = 0; dt < 2; ++dt)
            Ow[q * 256 + h * 32 + dt * 16 + l15] =
                (unsigned short)(ob[hh][qt * 2 + dt][j >> 1] >> ((j & 1) * 16));
        }
      }
  }
}

// ---------------- k_proj: x1 = x + LN(O @ Wp^T + b), dense 64x256, unshift scatter ----------------
__launch_bounds__(256)
__global__ void k_proj(const unsigned short* __restrict__ qkvO, const unsigned short* __restrict__ wp,
                       const float* __restrict__ proj_b, const float* __restrict__ n1w,
                       const float* __restrict__ n1b, const float* __restrict__ x,
                       float* __restrict__ x1) {
  const int mb = blockIdx.x;   // 784 blocks, 64 rows each
  const int t = threadIdx.x, lane = t & 63, w = t >> 6;
  const int l15 = lane & 15, g = lane >> 4, kk8 = g << 3, rj = g << 2;

  __shared__ __align__(16) char smem[46080];
  unsigned short* As = (unsigned short*)smem;           // [64][72]
  unsigned short* Bs = (unsigned short*)(smem + 9216);  // [256][72]

  f32x4 acc[16];
#pragma unroll
  for (int nf = 0; nf < 16; ++nf) acc[nf] = (f32x4){0.f, 0.f, 0.f, 0.f};

  for (int kb = 0; kb < 4; ++kb) {
    __syncthreads();
    {
      int ar = t >> 2, aq = t & 3;
      int row_g = mb * 64 + ar;
      int win = row_g / 49, r = row_g - win * 49;
      const unsigned short* sa = qkvO + (size_t)win * 37632 + r * 256 + kb * 64 + aq * 16;
      *(int4*)((char*)As + ar * 144 + aq * 32) = *(const int4*)sa;
      *(int4*)((char*)As + ar * 144 + aq * 32 + 16) = *(const int4*)(sa + 8);
      const unsigned short* sb = wp + (size_t)t * 256 + kb * 64;
#pragma unroll
      for (int c = 0; c < 8; ++c)
        *(int4*)((char*)Bs + t * 144 + c * 16) = *(const int4*)(sb + c * 8);
    }
    __syncthreads();
#pragma unroll
    for (int ks = 0; ks < 2; ++ks) {
      short8 a_ = *(const short8*)((char*)As + (w * 16 + l15) * 144 + (ks * 32 + kk8) * 2);
      short8 b_[16];
#pragma unroll
      for (int nf = 0; nf < 16; ++nf)
        b_[nf] = *(const short8*)((char*)Bs + (nf * 16 + l15) * 144 + (ks * 32 + kk8) * 2);
#pragma unroll
      for (int nf = 0; nf < 16; ++nf)
        acc[nf] = __builtin_amdgcn_mfma_f32_16x16x32_bf16(a_, b_[nf], acc[nf], 0, 0, 0);
    }
  }
#pragma unroll
  for (int nf = 0; nf < 16; ++nf) {
    float bias = proj_b[nf * 16 + l15];
#pragma unroll
    for (int j = 0; j < 4; ++j) acc[nf][j] += bias;
  }
#pragma unroll
  for (int j = 0; j < 4; ++j) {
    float s = 0.f, s2 = 0.f;
#pragma unroll
    for (int nf = 0; nf < 16; ++nf) {
      float v = acc[nf][j];
      s += v; s2 += v * v;
    }
    s += __shfl_xor(s, 1);  s += __shfl_xor(s, 2);  s += __shfl_xor(s, 4);  s += __shfl_xor(s, 8);
    s2 += __shfl_xor(s2, 1); s2 += __shfl_xor(s2, 2); s2 += __shfl_xor(s2, 4); s2 += __shfl_xor(s2, 8);
    float mu = s * (1.0f / 256.0f);
    float var = s2 * (1.0f / 256.0f) - mu * mu;
    float rs = rsqrtf(var + 1e-5f);
    int row_g = mb * 64 + w * 16 + rj + j;
    int win = row_g / 49, r = row_g - win * 49;
    int b = win >> 6, wi = (win >> 3) & 7, wj = win & 7;
    int i2 = r / 7, j2 = r - i2 * 7;
    int ho = (wi * 7 + i2 + 3) % 56, wo = (wj * 7 + j2 + 3) % 56;
    size_t base = (size_t)(b * 3136 + ho * 56 + wo) * 256;
#pragma unroll
    for (int nf = 0; nf < 16; ++nf) {
      int col = nf * 16 + l15;
      float xv = x[base + col];
      x1[base + col] = xv + (acc[nf][j] - mu) * rs * n1w[col] + n1b[col];
    }
  }
}

// ---------------- k_fc1: H = gelu(x1 @ W1^T + b1), 128x128 tile ----------------
__launch_bounds__(256)
__global__ void k_fc1(const float* __restrict__ x1, const unsigned short* __restrict__ w1,
                      const float* __restrict__ b1, unsigned short* __restrict__ Hbuf, int r0) {
  const int mb = blockIdx.x, nb = blockIdx.y;
  const int t = threadIdx.x, lane = t & 63, w = t >> 6;
  const int wm = w >> 1, wn = w & 1;
  const int l15 = lane & 15, kk8 = (lane >> 4) << 3, rj = (lane >> 4) << 2;

  __shared__ __align__(16) char smem[36864];
  unsigned short* As = (unsigned short*)smem;            // [128][72]
  unsigned short* Bs = (unsigned short*)(smem + 18432);  // [128][72]

  f32x4 acc[4][4];
#pragma unroll
  for (int mf = 0; mf < 4; ++mf)
#pragma unroll
    for (int nf = 0; nf < 4; ++nf) acc[mf][nf] = (f32x4){0.f, 0.f, 0.f, 0.f};

  const int row_g0 = r0 + mb * 128;
  const int srow = t >> 1, sh = t & 1;

  for (int kb = 0; kb < 4; ++kb) {
    __syncthreads();
    {
      const float* src = x1 + (size_t)(row_g0 + srow) * 256 + kb * 64 + sh * 32;
#pragma unroll
      for (int c = 0; c < 4; ++c) {
        float4 f0 = *(const float4*)(src + c * 8);
        float4 f1 = *(const float4*)(src + c * 8 + 4);
        int4 pk;
        pk.x = pk2(f0.x, f0.y);
        pk.y = pk2(f0.z, f0.w);
        pk.z = pk2(f1.x, f1.y);
        pk.w = pk2(f1.z, f1.w);
        *(int4*)((char*)As + srow * 144 + sh * 64 + c * 16) = pk;
      }
      const unsigned short* srcb = w1 + (size_t)(nb * 128 + srow) * 256 + kb * 64 + sh * 32;
#pragma unroll
      for (int c = 0; c < 4; ++c)
        *(int4*)((char*)Bs + srow * 144 + sh * 64 + c * 16) = *(const int4*)(srcb + c * 8);
    }
    __syncthreads();
#pragma unroll
    for (int ks = 0; ks < 2; ++ks) {
      int ko = ks * 32 + kk8;
      short8 a_[4], b_[4];
#pragma unroll
      for (int mf = 0; mf < 4; ++mf)
        a_[mf] = *(const short8*)((char*)As + (wm * 64 + mf * 16 + l15) * 144 + ko * 2);
#pragma unroll
      for (int nf = 0; nf < 4; ++nf)
        b_[nf] = *(const short8*)((char*)Bs + (wn * 64 + nf * 16 + l15) * 144 + ko * 2);
#pragma unroll
      for (int mf = 0; mf < 4; ++mf)
#pragma unroll
        for (int nf = 0; nf < 4; ++nf)
          acc[mf][nf] = __builtin_amdgcn_mfma_f32_16x16x32_bf16(a_[mf], b_[nf], acc[mf][nf], 0, 0, 0);
    }
  }
#pragma unroll
  for (int mf = 0; mf < 4; ++mf)
#pragma unroll
    for (int nf = 0; nf < 4; ++nf) {
      int col = nb * 128 + wn * 64 + nf * 16 + l15;
      float bias = b1[col];
#pragma unroll
      for (int j = 0; j < 4; ++j) {
        int row = mb * 128 + wm * 64 + mf * 16 + rj + j;
        Hbuf[(size_t)row * 1024 + col] = f2b(gelu_tanh(acc[mf][nf][j] + bias));
      }
    }
}

// ---------------- k_fc2: out = x1 + LN(H @ W2^T + b2), 64x256 tile, wave-local LN ----------------
__launch_bounds__(256)
__global__ void k_fc2(const unsigned short* __restrict__ Hbuf, const unsigned short* __restrict__ w2,
                      const float* __restrict__ b2, const float* __restrict__ n2w,
                      const float* __restrict__ n2b, float* __restrict__ xio, int r0) {
  const int mb = blockIdx.x;
  const int t = threadIdx.x, lane = t & 63, w = t >> 6;
  const int l15 = lane & 15, g = lane >> 4, kk8 = g << 3, rj = g << 2;

  __shared__ __align__(16) char smem[46080];
  unsigned short* As = (unsigned short*)smem;           // [64][72]
  unsigned short* Bs = (unsigned short*)(smem + 9216);  // [256][72]

  f32x4 acc[16];
#pragma unroll
  for (int nf = 0; nf < 16; ++nf) acc[nf] = (f32x4){0.f, 0.f, 0.f, 0.f};

  for (int kb = 0; kb < 16; ++kb) {
    __syncthreads();
    {
      int ar = t >> 2, aq = t & 3;
      const unsigned short* sa = Hbuf + (size_t)(mb * 64 + ar) * 1024 + kb * 64 + aq * 16;
      *(int4*)((char*)As + ar * 144 + aq * 32) = *(const int4*)sa;
      *(int4*)((char*)As + ar * 144 + aq * 32 + 16) = *(const int4*)(sa + 8);
      const unsigned short* sb = w2 + (size_t)t * 1024 + kb * 64;
#pragma unroll
      for (int c = 0; c < 8; ++c)
        *(int4*)((char*)Bs + t * 144 + c * 16) = *(const int4*)(sb + c * 8);
    }
    __syncthreads();
#pragma unroll
    for (int ks = 0; ks < 2; ++ks) {
      short8 a_ = *(const short8*)((char*)As + (w * 16 + l15) * 144 + (ks * 32 + kk8) * 2);
      short8 b_[16];
#pragma unroll
      for (int nf = 0; nf < 16; ++nf)
        b_[nf] = *(const short8*)((char*)Bs + (nf * 16 + l15) * 144 + (ks * 32 + kk8) * 2);
#pragma unroll
      for (int nf = 0; nf < 16; ++nf)
        acc[nf] = __builtin_amdgcn_mfma_f32_16x16x32_bf16(a_, b_[nf], acc[nf], 0, 0, 0);
    }
  }
#pragma unroll
  for (int nf = 0; nf < 16; ++nf) {
    float bias = b2[nf * 16 + l15];
#pragma unroll
    for (int j = 0; j < 4; ++j) acc[nf][j] += bias;
  }
#pragma unroll
  for (int j = 0; j < 4; ++j) {
    float s = 0.f, s2 = 0.f;
#pragma unroll
    for (int nf = 0; nf < 16; ++nf) {
      float v = acc[nf][j];
      s += v; s2 += v * v;
    }
    s += __shfl_xor(s, 1);  s += __shfl_xor(s, 2);  s += __shfl_xor(s, 4);  s += __shfl_xor(s, 8);
    s2 += __shfl_xor(s2, 1); s2 += __shfl_xor(s2, 2); s2 += __shfl_xor(s2, 4); s2 += __shfl_xor(s2, 8);
    float mu = s * (1.0f / 256.0f);
    float var = s2 * (1.0f / 256.0f) - mu * mu;
    float rs = rsqrtf(var + 1e-5f);
    size_t base = (size_t)(r0 + mb * 64 + w * 16 + rj + j) * 256;
#pragma unroll
    for (int nf = 0; nf < 16; ++nf) {
      int col = nf * 16 + l15;
      float xv = xio[base + col];
      xio[base + col] = xv + (acc[nf][j] - mu) * rs * n2w[col] + n2b[col];
    }
  }
}

extern "C" void kernel_launch(void* const* d_in, const int* in_sizes, int n_in,
                              void* d_out, int out_size, void* d_ws, size_t ws_size,
                              hipStream_t stream) {
  const float* x           = (const float*)d_in[0];
  const float* norm1_w     = (const float*)d_in[1];
  const float* norm1_b     = (const float*)d_in[2];
  const float* qkv_w       = (const float*)d_in[3];
  const float* q_bias      = (const float*)d_in[4];
  const float* v_bias      = (const float*)d_in[5];
  const float* logit_scale = (const float*)d_in[6];
  const float* cpb_w1      = (const float*)d_in[7];
  const float* cpb_b1      = (const float*)d_in[8];
  const float* cpb_w2      = (const float*)d_in[9];
  const float* proj_w      = (const float*)d_in[10];
  const float* proj_b      = (const float*)d_in[11];
  const float* norm2_w     = (const float*)d_in[12];
  const float* norm2_b     = (const float*)d_in[13];
  const float* fc1_w       = (const float*)d_in[14];
  const float* fc1_b       = (const float*)d_in[15];
  const float* fc2_w       = (const float*)d_in[16];
  const float* fc2_b       = (const float*)d_in[17];

  char* ws = (char*)d_ws;
  float*          scales  = (float*)(ws + 0);
  float*          tblg    = (float*)(ws + 64);
  unsigned short* wq      = (unsigned short*)(ws + 8192);    // dead after k_qkvg; biasT overlays
  float*          biasT   = (float*)(ws + 8192);
  unsigned short* wp      = (unsigned short*)(ws + 401408);
  unsigned short* w1b     = (unsigned short*)(ws + 532480);
  unsigned short* w2b     = (unsigned short*)(ws + 1056768);
  unsigned short* qkvbuf  = (unsigned short*)(ws + 1581056); // 77070336 B
  unsigned short* Hbuf    = (unsigned short*)(ws + 1581056); // reuses qkvbuf region (MLP phase)
  float*          x1      = (float*)d_out;
  unsigned short* xw      = (unsigned short*)d_out;          // dead before k_proj writes x1

  k_misc<<<dim3(1), dim3(256), 0, stream>>>(logit_scale, cpb_w1, cpb_b1, cpb_w2, scales, tblg);
  k_cvt<<<dim3(3072), dim3(256), 0, stream>>>(qkv_w, proj_w, fc1_w, fc2_w, wq, wp, w1b, w2b);
  k_xprep<<<dim3(6272), dim3(256), 0, stream>>>(x, xw);
  k_qkvg<<<dim3(392, 6), dim3(256), 0, stream>>>(xw, wq, q_bias, v_bias, scales, qkvbuf);
  k_bias<<<dim3(128), dim3(256), 0, stream>>>(tblg, biasT);
  k_attn2<<<dim3(1024), dim3(256), 0, stream>>>(qkvbuf, biasT);
  k_proj<<<dim3(784), dim3(256), 0, stream>>>(qkvbuf, wp, proj_b, norm1_w, norm1_b, x, x1);
  k_fc1<<<dim3(196, 8), dim3(256), 0, stream>>>(x1, w1b, fc1_b, Hbuf, 0);
  k_fc2<<<dim3(392), dim3(256), 0, stream>>>(Hbuf, w2b, fc2_b, norm2_w, norm2_b, x1, 0);
  k_fc1<<<dim3(196, 8), dim3(256), 0, stream>>>(x1, w1b, fc1_b, Hbuf, 25088);
  k_fc2<<<dim3(392), dim3(256), 0, stream>>>(Hbuf, w2b, fc2_b, norm2_w, norm2_b, x1, 25088);
}

// Round 8
// 438.952 us; speedup vs baseline: 1.4264x; 1.0558x over previous
//
#include <hip/hip_runtime.h>

typedef __attribute__((ext_vector_type(8))) short short8;
typedef __attribute__((ext_vector_type(4))) float f32x4;

union I4S8 { int4 i; short8 s; };

__device__ __forceinline__ unsigned short f2b(float f) {
  unsigned u = __float_as_uint(f);
  return (unsigned short)((u + 0x7FFFu + ((u >> 16) & 1u)) >> 16);
}
__device__ __forceinline__ unsigned pk2(float a, float b) {
  return (unsigned)f2b(a) | ((unsigned)f2b(b) << 16);
}
__device__ __forceinline__ float b2f(unsigned short h) {
  return __uint_as_float(((unsigned)h) << 16);
}
__device__ __forceinline__ float gelu_tanh(float v) {
  float c = 0.7978845608028654f * (v + 0.044715f * v * v * v);
  return 0.5f * v * (1.0f + tanhf(c));
}

// ---------------- k_misc: scales + CPB table (raw, per rel-coord) ----------------
__global__ void k_misc(const float* __restrict__ logit_scale,
                       const float* __restrict__ w1, const float* __restrict__ b1,
                       const float* __restrict__ w2,
                       float* __restrict__ scales, float* __restrict__ tblg) {
  int t = threadIdx.x;
  if (t < 8) scales[t] = expf(fminf(logit_scale[t], logf(100.0f)));
  if (t < 169) {
    int a = t / 13, b = t % 13;
    float ra = (float)(a - 6) * (8.0f / 6.0f);
    float rb = (float)(b - 6) * (8.0f / 6.0f);
    float sa = (ra > 0.f) ? 1.f : ((ra < 0.f) ? -1.f : 0.f);
    float sb = (rb > 0.f) ? 1.f : ((rb < 0.f) ? -1.f : 0.f);
    float t0 = sa * log2f(fabsf(ra) + 1.0f) / 3.0f;
    float t1 = sb * log2f(fabsf(rb) + 1.0f) / 3.0f;
    float acc[8];
#pragma unroll
    for (int hh = 0; hh < 8; ++hh) acc[hh] = 0.f;
    for (int j = 0; j < 512; ++j) {
      float hv = fmaxf(w1[2*j] * t0 + w1[2*j+1] * t1 + b1[j], 0.0f);
#pragma unroll
      for (int hh = 0; hh < 8; ++hh) acc[hh] += w2[hh*512 + j] * hv;
    }
#pragma unroll
    for (int hh = 0; hh < 8; ++hh) tblg[t * 8 + hh] = acc[hh];
  }
}

// ---------------- k_bias: biasT[h][k][q] padded 64x64, pad=-3e8 ----------------
__global__ void k_bias(const float* __restrict__ tblg, float* __restrict__ biasT) {
  int idx = blockIdx.x * 256 + threadIdx.x;   // 8*64*64 = 32768
  int h = idx >> 12, rem = idx & 4095, k = rem >> 6, q = rem & 63;
  float v;
  if (k >= 49 || q >= 49) {
    v = -3.0e8f;
  } else {
    int e = (q / 7 - k / 7 + 6) * 13 + (q % 7 - k % 7 + 6);
    float r = tblg[e * 8 + h];
    v = 16.0f / (1.0f + expf(-r));
  }
  biasT[idx] = v;
}

// ---------------- k_cvt: weights fp32 -> bf16 ----------------
__global__ void k_cvt(const float* __restrict__ qkv_w, const float* __restrict__ proj_w,
                      const float* __restrict__ fc1_w, const float* __restrict__ fc2_w,
                      unsigned short* __restrict__ wq, unsigned short* __restrict__ wp,
                      unsigned short* __restrict__ w1, unsigned short* __restrict__ w2) {
  int i = blockIdx.x * 256 + threadIdx.x;
  if (i < 196608) wq[i] = f2b(qkv_w[i]);
  else if (i < 262144) wp[i - 196608] = f2b(proj_w[i - 196608]);
  else if (i < 524288) w1[i - 262144] = f2b(fc1_w[i - 262144]);
  else w2[i - 524288] = f2b(fc2_w[i - 524288]);
}

// ---------------- k_xprep: shifted-window gather x -> xw[50176][256] bf16 ----------------
__global__ void k_xprep(const float* __restrict__ x, unsigned short* __restrict__ xw) {
  int id = blockIdx.x * 256 + threadIdx.x;
  int row = id >> 5, c8 = (id & 31) << 3;
  int win = row / 49, r = row - win * 49;
  int b = win >> 6, wi = (win >> 3) & 7, wj = win & 7;
  int i = r / 7, j = r - i * 7;
  int ho = (wi * 7 + i + 3) % 56;
  int wo = (wj * 7 + j + 3) % 56;
  const float* src = x + (size_t)(b * 3136 + ho * 56 + wo) * 256 + c8;
  float4 f0 = *(const float4*)(src);
  float4 f1 = *(const float4*)(src + 4);
  int4 pk;
  pk.x = pk2(f0.x, f0.y);
  pk.y = pk2(f0.z, f0.w);
  pk.z = pk2(f1.x, f1.y);
  pk.w = pk2(f1.z, f1.w);
  *(int4*)(xw + (size_t)row * 256 + c8) = pk;
}

// ---------------- k_xb: x1 f32 -> xb bf16 (row-linear) ----------------
__global__ void k_xb(const float* __restrict__ x1, unsigned short* __restrict__ xb) {
  int id = blockIdx.x * 256 + threadIdx.x;
  size_t off = (size_t)id << 3;
  const float* src = x1 + off;
  float4 f0 = *(const float4*)(src);
  float4 f1 = *(const float4*)(src + 4);
  int4 pk;
  pk.x = pk2(f0.x, f0.y);
  pk.y = pk2(f0.z, f0.w);
  pk.z = pk2(f1.x, f1.y);
  pk.w = pk2(f1.z, f1.w);
  *(int4*)(xb + off) = pk;
}

// ---------------- k_qkvg: dense QKV GEMM 50176x768x256 + fused q/k norm ----------------
__launch_bounds__(256)
__global__ void k_qkvg(const unsigned short* __restrict__ xw, const unsigned short* __restrict__ wq,
                       const float* __restrict__ q_bias, const float* __restrict__ v_bias,
                       const float* __restrict__ scales, unsigned short* __restrict__ qkv) {
  const int mb = blockIdx.x, nb = blockIdx.y;   // 392 x 6
  const int t = threadIdx.x, lane = t & 63, w = t >> 6;
  const int wm = w >> 1, wn = w & 1;
  const int l15 = lane & 15, kk8 = (lane >> 4) << 3, rj = (lane >> 4) << 2;

  __shared__ __align__(16) char smem[36864];
  unsigned short* As = (unsigned short*)smem;            // [128][72]
  unsigned short* Bs = (unsigned short*)(smem + 18432);  // [128][72]

  f32x4 acc[4][4];
#pragma unroll
  for (int mf = 0; mf < 4; ++mf)
#pragma unroll
    for (int nf = 0; nf < 4; ++nf) acc[mf][nf] = (f32x4){0.f, 0.f, 0.f, 0.f};

  const int srow = t >> 1, sh = t & 1;
  for (int kb = 0; kb < 4; ++kb) {
    __syncthreads();
    {
      const unsigned short* sa = xw + (size_t)(mb * 128 + srow) * 256 + kb * 64 + sh * 32;
#pragma unroll
      for (int c = 0; c < 4; ++c)
        *(int4*)((char*)As + srow * 144 + sh * 64 + c * 16) = *(const int4*)(sa + c * 8);
      const unsigned short* sb = wq + (size_t)(nb * 128 + srow) * 256 + kb * 64 + sh * 32;
#pragma unroll
      for (int c = 0; c < 4; ++c)
        *(int4*)((char*)Bs + srow * 144 + sh * 64 + c * 16) = *(const int4*)(sb + c * 8);
    }
    __syncthreads();
#pragma unroll
    for (int ks = 0; ks < 2; ++ks) {
      int ko = ks * 32 + kk8;
      short8 a_[4], b_[4];
#pragma unroll
      for (int mf = 0; mf < 4; ++mf)
        a_[mf] = *(const short8*)((char*)As + (wm * 64 + mf * 16 + l15) * 144 + ko * 2);
#pragma unroll
      for (int nf = 0; nf < 4; ++nf)
        b_[nf] = *(const short8*)((char*)Bs + (wn * 64 + nf * 16 + l15) * 144 + ko * 2);
#pragma unroll
      for (int mf = 0; mf < 4; ++mf)
#pragma unroll
        for (int nf = 0; nf < 4; ++nf)
          acc[mf][nf] = __builtin_amdgcn_mfma_f32_16x16x32_bf16(a_[mf], b_[nf], acc[mf][nf], 0, 0, 0);
    }
  }

  const int which = nb >> 1;
  if (which != 1) {
    const float* bp = (which == 0) ? q_bias : v_bias;
#pragma unroll
    for (int nf = 0; nf < 4; ++nf) {
      float bias = bp[(nb & 1) * 128 + wn * 64 + nf * 16 + l15];
#pragma unroll
      for (int mf = 0; mf < 4; ++mf)
#pragma unroll
        for (int j = 0; j < 4; ++j) acc[mf][nf][j] += bias;
    }
  }
  if (which < 2) {
#pragma unroll
    for (int mf = 0; mf < 4; ++mf)
#pragma unroll
      for (int p = 0; p < 2; ++p)
#pragma unroll
        for (int j = 0; j < 4; ++j) {
          float ss = acc[mf][2*p][j] * acc[mf][2*p][j] + acc[mf][2*p+1][j] * acc[mf][2*p+1][j];
          ss += __shfl_xor(ss, 1); ss += __shfl_xor(ss, 2);
          ss += __shfl_xor(ss, 4); ss += __shfl_xor(ss, 8);
          float inv = 1.0f / fmaxf(sqrtf(ss), 1e-12f);
          if (which == 0) inv *= scales[(nb & 1) * 4 + wn * 2 + p];
          acc[mf][2*p][j] *= inv;
          acc[mf][2*p+1][j] *= inv;
        }
  }
  const int head = (nb & 1) * 4 + wn * 2;
#pragma unroll
  for (int mf = 0; mf < 4; ++mf)
#pragma unroll
    for (int j = 0; j < 4; ++j) {
      int row_g = mb * 128 + wm * 64 + mf * 16 + rj + j;
      int win = row_g / 49, r = row_g - win * 49;
      size_t base = (((size_t)win * 3 + which) * 8) * 1568;
#pragma unroll
      for (int nf = 0; nf < 4; ++nf) {
        int h = head + (nf >> 1), d = (nf & 1) * 16 + l15;
        qkv[base + (size_t)h * 1568 + r * 32 + d] = f2b(acc[mf][nf][j]);
      }
    }
}

// ---------------- k_attn2: attention only; O overwrites the q-slice as [49][256] ----------------
__launch_bounds__(256, 3)
__global__ void k_attn2(unsigned short* __restrict__ qkv, const float* __restrict__ biasT) {
  const int win = blockIdx.x;
  const int wi = (win >> 3) & 7, wj = win & 7;
  const int t = threadIdx.x, lane = t & 63, w = t >> 6;
  const int l15 = lane & 15, g = lane >> 4;
  const int kk8 = g << 3, rj = g << 2;

  __shared__ __align__(16) unsigned short VT8[8 * 32 * 72];   // 36864 B

  const int vi = (wi == 7) ? 1 : 0, vj = (wj == 7) ? 1 : 0;

  for (int idx = t; idx < 392; idx += 256) {
    int h = idx / 49, r = idx % 49;
    const unsigned short* vp = qkv + ((((size_t)win * 3 + 2) * 8 + h) * 49 + r) * 32;
    unsigned short vv[32];
    *(int4*)(vv + 0)  = *(const int4*)(vp + 0);
    *(int4*)(vv + 8)  = *(const int4*)(vp + 8);
    *(int4*)(vv + 16) = *(const int4*)(vp + 16);
    *(int4*)(vv + 24) = *(const int4*)(vp + 24);
    unsigned short* dst = VT8 + h * 2304;
#pragma unroll
    for (int d = 0; d < 32; ++d) dst[d * 72 + r] = vv[d];
  }
  for (int idx = t; idx < 3840; idx += 256) {
    int h = idx / 480, rem = idx % 480, d = rem / 15, r = 49 + rem % 15;
    VT8[h * 2304 + d * 72 + r] = 0;
  }
  __syncthreads();

  const int sA = l15 + ((g & 1) << 5);
  const int sB = sA + 16;
  const bool hi = ((g >> 1) & 1) != 0;

  unsigned ob[2][8][2];
  for (int hh = 0; hh < 2; ++hh) {
    const int h = w + hh * 4;
    const float* bT = biasT + (size_t)h * 4096;
    f32x4 s[4][4];
#pragma unroll
    for (int mf = 0; mf < 4; ++mf)
#pragma unroll
      for (int nf = 0; nf < 4; ++nf)
#pragma unroll
        for (int j = 0; j < 4; ++j)
          s[mf][nf][j] = bT[(mf * 16 + rj + j) * 64 + nf * 16 + l15];
    if (vi | vj) {
      int rq[4];
#pragma unroll
      for (int nf = 0; nf < 4; ++nf) {
        int q = nf * 16 + l15, qi = q / 7, qj = q - qi * 7;
        int aq = vi ? (qi < 4 ? 1 : 2) : 0;
        int bq = vj ? (qj < 4 ? 1 : 2) : 0;
        rq[nf] = aq * 3 + bq;
      }
#pragma unroll
      for (int mf = 0; mf < 4; ++mf)
#pragma unroll
        for (int j = 0; j < 4; ++j) {
          int k = mf * 16 + rj + j, ki = k / 7, kj = k - ki * 7;
          int ak = vi ? (ki < 4 ? 1 : 2) : 0;
          int bk = vj ? (kj < 4 ? 1 : 2) : 0;
          int rk = ak * 3 + bk;
#pragma unroll
          for (int nf = 0; nf < 4; ++nf)
            if (rq[nf] != rk) s[mf][nf][j] -= 100.0f;
        }
    }
    const unsigned short* kp = qkv + (((size_t)win * 3 + 1) * 8 + h) * 1568;
    const unsigned short* qp = qkv + (((size_t)win * 3 + 0) * 8 + h) * 1568;
    short8 ka[4], qa[4];
#pragma unroll
    for (int f = 0; f < 4; ++f) {
      ka[f] = *(const short8*)(kp + (f * 16 + l15) * 32 + kk8);
      qa[f] = *(const short8*)(qp + (f * 16 + l15) * 32 + kk8);
    }
#pragma unroll
    for (int mf = 0; mf < 4; ++mf)
#pragma unroll
      for (int nf = 0; nf < 4; ++nf)
        s[mf][nf] = __builtin_amdgcn_mfma_f32_16x16x32_bf16(ka[mf], qa[nf], s[mf][nf], 0, 0, 0);

    unsigned D[4][4][2];
#pragma unroll
    for (int nf = 0; nf < 4; ++nf) {
      float m = -3.0e8f;
#pragma unroll
      for (int mf = 0; mf < 4; ++mf)
#pragma unroll
        for (int j = 0; j < 4; ++j) m = fmaxf(m, s[mf][nf][j]);
      m = fmaxf(m, __shfl_xor(m, 16));
      m = fmaxf(m, __shfl_xor(m, 32));
      float sum = 0.f;
#pragma unroll
      for (int mf = 0; mf < 4; ++mf)
#pragma unroll
        for (int j = 0; j < 4; ++j) {
          float e = __expf(s[mf][nf][j] - m);
          s[mf][nf][j] = e; sum += e;
        }
      sum += __shfl_xor(sum, 16);
      sum += __shfl_xor(sum, 32);
      float inv = 1.0f / sum;
#pragma unroll
      for (int mf = 0; mf < 4; ++mf) {
        D[mf][nf][0] = pk2(s[mf][nf][0] * inv, s[mf][nf][1] * inv);
        D[mf][nf][1] = pk2(s[mf][nf][2] * inv, s[mf][nf][3] * inv);
      }
    }

    f32x4 o[8];
#pragma unroll
    for (int i = 0; i < 8; ++i) o[i] = (f32x4){0.f, 0.f, 0.f, 0.f};
#pragma unroll
    for (int ks = 0; ks < 2; ++ks) {
      short8 vb[2];
#pragma unroll
      for (int dt = 0; dt < 2; ++dt)
        vb[dt] = *(const short8*)(VT8 + h * 2304 + (dt * 16 + l15) * 72 + ks * 32 + kk8);
#pragma unroll
      for (int qt = 0; qt < 4; ++qt) {
        int a0 = __shfl((int)D[2*ks+0][qt][0], sA), a1 = __shfl((int)D[2*ks+1][qt][0], sA);
        int b0 = __shfl((int)D[2*ks+0][qt][1], sA), b1 = __shfl((int)D[2*ks+1][qt][1], sA);
        int c0 = __shfl((int)D[2*ks+0][qt][0], sB), c1 = __shfl((int)D[2*ks+1][qt][0], sB);
        int e0 = __shfl((int)D[2*ks+0][qt][1], sB), e1 = __shfl((int)D[2*ks+1][qt][1], sB);
        I4S8 u;
        u.i.x = hi ? a1 : a0;
        u.i.y = hi ? b1 : b0;
        u.i.z = hi ? c1 : c0;
        u.i.w = hi ? e1 : e0;
#pragma unroll
        for (int dt = 0; dt < 2; ++dt)
          o[qt * 2 + dt] = __builtin_amdgcn_mfma_f32_16x16x32_bf16(u.s, vb[dt], o[qt * 2 + dt], 0, 0, 0);
      }
    }
#pragma unroll
    for (int f = 0; f < 8; ++f) {
      ob[hh][f][0] = pk2(o[f][0], o[f][1]);
      ob[hh][f][1] = pk2(o[f][2], o[f][3]);
    }
  }
  __syncthreads();

  unsigned short* Ow = qkv + (size_t)win * 37632;
#pragma unroll
  for (int hh = 0; hh < 2; ++hh) {
    int h = w + hh * 4;
#pragma unroll
    for (int qt = 0; qt < 4; ++qt)
#pragma unroll
      for (int j = 0; j < 4; ++j) {
        int q = qt * 16 + rj + j;
        if (q < 49) {
#pragma unroll
          for (int dt = 0; dt < 2; ++dt)
            Ow[q * 256 + h * 32 + dt * 16 + l15] =
                (unsigned short)(ob[hh][qt * 2 + dt][j >> 1] >> ((j & 1) * 16));
        }
      }
  }
}

// ---------------- k_proj: x1 = x + LN(O @ Wp^T + b), dense 64x256, unshift scatter ----------------
__launch_bounds__(256)
__global__ void k_proj(const unsigned short* __restrict__ qkvO, const unsigned short* __restrict__ wp,
                       const float* __restrict__ proj_b, const float* __restrict__ n1w,
                       const float* __restrict__ n1b, const float* __restrict__ x,
                       float* __restrict__ x1) {
  const int mb = blockIdx.x;
  const int t = threadIdx.x, lane = t & 63, w = t >> 6;
  const int l15 = lane & 15, g = lane >> 4, kk8 = g << 3, rj = g << 2;

  __shared__ __align__(16) char smem[46080];
  unsigned short* As = (unsigned short*)smem;           // [64][72]
  unsigned short* Bs = (unsigned short*)(smem + 9216);  // [256][72]

  f32x4 acc[16];
#pragma unroll
  for (int nf = 0; nf < 16; ++nf) acc[nf] = (f32x4){0.f, 0.f, 0.f, 0.f};

  for (int kb = 0; kb < 4; ++kb) {
    __syncthreads();
    {
      int ar = t >> 2, aq = t & 3;
      int row_g = mb * 64 + ar;
      int win = row_g / 49, r = row_g - win * 49;
      const unsigned short* sa = qkvO + (size_t)win * 37632 + r * 256 + kb * 64 + aq * 16;
      *(int4*)((char*)As + ar * 144 + aq * 32) = *(const int4*)sa;
      *(int4*)((char*)As + ar * 144 + aq * 32 + 16) = *(const int4*)(sa + 8);
      const unsigned short* sb = wp + (size_t)t * 256 + kb * 64;
#pragma unroll
      for (int c = 0; c < 8; ++c)
        *(int4*)((char*)Bs + t * 144 + c * 16) = *(const int4*)(sb + c * 8);
    }
    __syncthreads();
#pragma unroll
    for (int ks = 0; ks < 2; ++ks) {
      short8 a_ = *(const short8*)((char*)As + (w * 16 + l15) * 144 + (ks * 32 + kk8) * 2);
      short8 b_[16];
#pragma unroll
      for (int nf = 0; nf < 16; ++nf)
        b_[nf] = *(const short8*)((char*)Bs + (nf * 16 + l15) * 144 + (ks * 32 + kk8) * 2);
#pragma unroll
      for (int nf = 0; nf < 16; ++nf)
        acc[nf] = __builtin_amdgcn_mfma_f32_16x16x32_bf16(a_, b_[nf], acc[nf], 0, 0, 0);
    }
  }
#pragma unroll
  for (int nf = 0; nf < 16; ++nf) {
    float bias = proj_b[nf * 16 + l15];
#pragma unroll
    for (int j = 0; j < 4; ++j) acc[nf][j] += bias;
  }
#pragma unroll
  for (int j = 0; j < 4; ++j) {
    float s = 0.f, s2 = 0.f;
#pragma unroll
    for (int nf = 0; nf < 16; ++nf) {
      float v = acc[nf][j];
      s += v; s2 += v * v;
    }
    s += __shfl_xor(s, 1);  s += __shfl_xor(s, 2);  s += __shfl_xor(s, 4);  s += __shfl_xor(s, 8);
    s2 += __shfl_xor(s2, 1); s2 += __shfl_xor(s2, 2); s2 += __shfl_xor(s2, 4); s2 += __shfl_xor(s2, 8);
    float mu = s * (1.0f / 256.0f);
    float var = s2 * (1.0f / 256.0f) - mu * mu;
    float rs = rsqrtf(var + 1e-5f);
    int row_g = mb * 64 + w * 16 + rj + j;
    int win = row_g / 49, r = row_g - win * 49;
    int b = win >> 6, wi = (win >> 3) & 7, wj = win & 7;
    int i2 = r / 7, j2 = r - i2 * 7;
    int ho = (wi * 7 + i2 + 3) % 56, wo = (wj * 7 + j2 + 3) % 56;
    size_t base = (size_t)(b * 3136 + ho * 56 + wo) * 256;
#pragma unroll
    for (int nf = 0; nf < 16; ++nf) {
      int col = nf * 16 + l15;
      float xv = x[base + col];
      x1[base + col] = xv + (acc[nf][j] - mu) * rs * n1w[col] + n1b[col];
    }
  }
}

// ---------------- k_fc1: H = gelu(xb @ W1^T + b1), 128x128 tile, bf16 A ----------------
__launch_bounds__(256)
__global__ void k_fc1(const unsigned short* __restrict__ xb, const unsigned short* __restrict__ w1,
                      const float* __restrict__ b1, unsigned short* __restrict__ Hbuf, int r0) {
  const int mb = blockIdx.x, nb = blockIdx.y;
  const int t = threadIdx.x, lane = t & 63, w = t >> 6;
  const int wm = w >> 1, wn = w & 1;
  const int l15 = lane & 15, kk8 = (lane >> 4) << 3, rj = (lane >> 4) << 2;

  __shared__ __align__(16) char smem[36864];
  unsigned short* As = (unsigned short*)smem;            // [128][72]
  unsigned short* Bs = (unsigned short*)(smem + 18432);  // [128][72]

  f32x4 acc[4][4];
#pragma unroll
  for (int mf = 0; mf < 4; ++mf)
#pragma unroll
    for (int nf = 0; nf < 4; ++nf) acc[mf][nf] = (f32x4){0.f, 0.f, 0.f, 0.f};

  const int row_g0 = r0 + mb * 128;
  const int srow = t >> 1, sh = t & 1;

  for (int kb = 0; kb < 4; ++kb) {
    __syncthreads();
    {
      const unsigned short* sa = xb + (size_t)(row_g0 + srow) * 256 + kb * 64 + sh * 32;
#pragma unroll
      for (int c = 0; c < 4; ++c)
        *(int4*)((char*)As + srow * 144 + sh * 64 + c * 16) = *(const int4*)(sa + c * 8);
      const unsigned short* srcb = w1 + (size_t)(nb * 128 + srow) * 256 + kb * 64 + sh * 32;
#pragma unroll
      for (int c = 0; c < 4; ++c)
        *(int4*)((char*)Bs + srow * 144 + sh * 64 + c * 16) = *(const int4*)(srcb + c * 8);
    }
    __syncthreads();
#pragma unroll
    for (int ks = 0; ks < 2; ++ks) {
      int ko = ks * 32 + kk8;
      short8 a_[4], b_[4];
#pragma unroll
      for (int mf = 0; mf < 4; ++mf)
        a_[mf] = *(const short8*)((char*)As + (wm * 64 + mf * 16 + l15) * 144 + ko * 2);
#pragma unroll
      for (int nf = 0; nf < 4; ++nf)
        b_[nf] = *(const short8*)((char*)Bs + (wn * 64 + nf * 16 + l15) * 144 + ko * 2);
#pragma unroll
      for (int mf = 0; mf < 4; ++mf)
#pragma unroll
        for (int nf = 0; nf < 4; ++nf)
          acc[mf][nf] = __builtin_amdgcn_mfma_f32_16x16x32_bf16(a_[mf], b_[nf], acc[mf][nf], 0, 0, 0);
    }
  }
#pragma unroll
  for (int mf = 0; mf < 4; ++mf)
#pragma unroll
    for (int nf = 0; nf < 4; ++nf) {
      int col = nb * 128 + wn * 64 + nf * 16 + l15;
      float bias = b1[col];
#pragma unroll
      for (int j = 0; j < 4; ++j) {
        int row = mb * 128 + wm * 64 + mf * 16 + rj + j;
        Hbuf[(size_t)row * 1024 + col] = f2b(gelu_tanh(acc[mf][nf][j] + bias));
      }
    }
}

// ---------------- k_fc2: out = x1 + LN(H @ W2^T + b2), 64x256 tile, wave-local LN ----------------
__launch_bounds__(256)
__global__ void k_fc2(const unsigned short* __restrict__ Hbuf, const unsigned short* __restrict__ w2,
                      const float* __restrict__ b2, const float* __restrict__ n2w,
                      const float* __restrict__ n2b, float* __restrict__ xio, int r0) {
  const int mb = blockIdx.x;
  const int t = threadIdx.x, lane = t & 63, w = t >> 6;
  const int l15 = lane & 15, g = lane >> 4, kk8 = g << 3, rj = g << 2;

  __shared__ __align__(16) char smem[46080];
  unsigned short* As = (unsigned short*)smem;           // [64][72]
  unsigned short* Bs = (unsigned short*)(smem + 9216);  // [256][72]

  f32x4 acc[16];
#pragma unroll
  for (int nf = 0; nf < 16; ++nf) acc[nf] = (f32x4){0.f, 0.f, 0.f, 0.f};

  for (int kb = 0; kb < 16; ++kb) {
    __syncthreads();
    {
      int ar = t >> 2, aq = t & 3;
      const unsigned short* sa = Hbuf + (size_t)(mb * 64 + ar) * 1024 + kb * 64 + aq * 16;
      *(int4*)((char*)As + ar * 144 + aq * 32) = *(const int4*)sa;
      *(int4*)((char*)As + ar * 144 + aq * 32 + 16) = *(const int4*)(sa + 8);
      const unsigned short* sb = w2 + (size_t)t * 1024 + kb * 64;
#pragma unroll
      for (int c = 0; c < 8; ++c)
        *(int4*)((char*)Bs + t * 144 + c * 16) = *(const int4*)(sb + c * 8);
    }
    __syncthreads();
#pragma unroll
    for (int ks = 0; ks < 2; ++ks) {
      short8 a_ = *(const short8*)((char*)As + (w * 16 + l15) * 144 + (ks * 32 + kk8) * 2);
      short8 b_[16];
#pragma unroll
      for (int nf = 0; nf < 16; ++nf)
        b_[nf] = *(const short8*)((char*)Bs + (nf * 16 + l15) * 144 + (ks * 32 + kk8) * 2);
#pragma unroll
      for (int nf = 0; nf < 16; ++nf)
        acc[nf] = __builtin_amdgcn_mfma_f32_16x16x32_bf16(a_, b_[nf], acc[nf], 0, 0, 0);
    }
  }
#pragma unroll
  for (int nf = 0; nf < 16; ++nf) {
    float bias = b2[nf * 16 + l15];
#pragma unroll
    for (int j = 0; j < 4; ++j) acc[nf][j] += bias;
  }
#pragma unroll
  for (int j = 0; j < 4; ++j) {
    float s = 0.f, s2 = 0.f;
#pragma unroll
    for (int nf = 0; nf < 16; ++nf) {
      float v = acc[nf][j];
      s += v; s2 += v * v;
    }
    s += __shfl_xor(s, 1);  s += __shfl_xor(s, 2);  s += __shfl_xor(s, 4);  s += __shfl_xor(s, 8);
    s2 += __shfl_xor(s2, 1); s2 += __shfl_xor(s2, 2); s2 += __shfl_xor(s2, 4); s2 += __shfl_xor(s2, 8);
    float mu = s * (1.0f / 256.0f);
    float var = s2 * (1.0f / 256.0f) - mu * mu;
    float rs = rsqrtf(var + 1e-5f);
    size_t base = (size_t)(r0 + mb * 64 + w * 16 + rj + j) * 256;
#pragma unroll
    for (int nf = 0; nf < 16; ++nf) {
      int col = nf * 16 + l15;
      float xv = xio[base + col];
      xio[base + col] = xv + (acc[nf][j] - mu) * rs * n2w[col] + n2b[col];
    }
  }
}

extern "C" void kernel_launch(void* const* d_in, const int* in_sizes, int n_in,
                              void* d_out, int out_size, void* d_ws, size_t ws_size,
                              hipStream_t stream) {
  const float* x           = (const float*)d_in[0];
  const float* norm1_w     = (const float*)d_in[1];
  const float* norm1_b     = (const float*)d_in[2];
  const float* qkv_w       = (const float*)d_in[3];
  const float* q_bias      = (const float*)d_in[4];
  const float* v_bias      = (const float*)d_in[5];
  const float* logit_scale = (const float*)d_in[6];
  const float* cpb_w1      = (const float*)d_in[7];
  const float* cpb_b1      = (const float*)d_in[8];
  const float* cpb_w2      = (const float*)d_in[9];
  const float* proj_w      = (const float*)d_in[10];
  const float* proj_b      = (const float*)d_in[11];
  const float* norm2_w     = (const float*)d_in[12];
  const float* norm2_b     = (const float*)d_in[13];
  const float* fc1_w       = (const float*)d_in[14];
  const float* fc1_b       = (const float*)d_in[15];
  const float* fc2_w       = (const float*)d_in[16];
  const float* fc2_b       = (const float*)d_in[17];

  char* ws = (char*)d_ws;
  float*          scales  = (float*)(ws + 0);
  float*          tblg    = (float*)(ws + 64);
  unsigned short* wq      = (unsigned short*)(ws + 8192);    // dead after k_qkvg; biasT overlays
  float*          biasT   = (float*)(ws + 8192);
  unsigned short* wp      = (unsigned short*)(ws + 401408);
  unsigned short* w1b     = (unsigned short*)(ws + 532480);
  unsigned short* w2b     = (unsigned short*)(ws + 1056768);
  unsigned short* qkvbuf  = (unsigned short*)(ws + 1581056); // 77070336 B (attn phase)
  // MLP phase (qkvbuf dead): xb 25.7MB then Hbuf 51.4MB — exactly the qkvbuf footprint
  unsigned short* xb      = (unsigned short*)(ws + 1581056);
  unsigned short* Hbuf    = (unsigned short*)(ws + 27271168);
  float*          x1      = (float*)d_out;
  unsigned short* xw      = (unsigned short*)d_out;          // dead before k_proj writes x1

  k_misc<<<dim3(1), dim3(256), 0, stream>>>(logit_scale, cpb_w1, cpb_b1, cpb_w2, scales, tblg);
  k_cvt<<<dim3(3072), dim3(256), 0, stream>>>(qkv_w, proj_w, fc1_w, fc2_w, wq, wp, w1b, w2b);
  k_xprep<<<dim3(6272), dim3(256), 0, stream>>>(x, xw);
  k_qkvg<<<dim3(392, 6), dim3(256), 0, stream>>>(xw, wq, q_bias, v_bias, scales, qkvbuf);
  k_bias<<<dim3(128), dim3(256), 0, stream>>>(tblg, biasT);
  k_attn2<<<dim3(1024), dim3(256), 0, stream>>>(qkvbuf, biasT);
  k_proj<<<dim3(784), dim3(256), 0, stream>>>(qkvbuf, wp, proj_b, norm1_w, norm1_b, x, x1);
  k_xb<<<dim3(6272), dim3(256), 0, stream>>>(x1, xb);
  k_fc1<<<dim3(196, 8), dim3(256), 0, stream>>>(xb, w1b, fc1_b, Hbuf, 0);
  k_fc2<<<dim3(392), dim3(256), 0, stream>>>(Hbuf, w2b, fc2_b, norm2_w, norm2_b, x1, 0);
  k_fc1<<<dim3(196, 8), dim3(256), 0, stream>>>(xb, w1b, fc1_b, Hbuf, 25088);
  k_fc2<<<dim3(392), dim3(256), 0, stream>>>(Hbuf, w2b, fc2_b, norm2_w, norm2_b, x1, 25088);
}